// Round 7
// baseline (769.569 us; speedup 1.0000x reference)
//
#include <hip/hip_runtime.h>
#include <stdint.h>

#define NN 50000
#define NE 800000
// IN=128, HID=256, LAT=64

typedef unsigned short ushort_t;

__device__ inline float bf2f(uint16_t u) {
    union { uint32_t i; float f; } v; v.i = ((uint32_t)u) << 16; return v.f;
}
__device__ inline uint16_t f2bf(float f) {
    uint32_t u = __float_as_uint(f);
    u += 0x7fffu + ((u >> 16) & 1u);
    return (uint16_t)(u >> 16);
}
__device__ inline float rdf(const void* p, int i, int bf) {
    return bf ? bf2f(((const ushort_t*)p)[i]) : ((const float*)p)[i];
}

// ---------------- edge dtype detection (int64 vs int32 storage) ----------------
__global__ __launch_bounds__(256) void k_detect(const int* __restrict__ ei, int* __restrict__ mode) {
    __shared__ int nz;
    if (threadIdx.x == 0) nz = 0;
    __syncthreads();
    int t = threadIdx.x;
    int v = ei[2 * t + 1] | ei[2 * (t + 256) + 1] | ei[2 * (t + 512) + 1] | ei[2 * (t + 768) + 1];
    if (v) atomicOr(&nz, 1);
    __syncthreads();
    if (t == 0) *mode = (nz == 0) ? 1 : 0;   // 1 => int64 (stride-2 words), 0 => int32
}

// ---------------- float dtype detection (f32 vs bf16 storage) ----------------
__global__ __launch_bounds__(256) void k_dtypef(const ushort_t* __restrict__ xw, int* __restrict__ fmode) {
    __shared__ int bad;
    if (threadIdx.x == 0) bad = 0;
    __syncthreads();
    int t = threadIdx.x;
#pragma unroll
    for (int r = 0; r < 2; ++r) {
        uint16_t w = xw[t + 256 * r];
        int e = (w >> 7) & 0xFF;
        if (!(w == 0 || (e >= 96 && e <= 144))) atomicOr(&bad, 1);
    }
    __syncthreads();
    if (t == 0) *fmode = (bad == 0) ? 1 : 0;   // 1 => bf16 storage, 0 => f32 storage
}

// ---------------- CSR build ----------------
__global__ __launch_bounds__(256) void k_degree(const int* __restrict__ ei, const int* __restrict__ mode,
                                                int* __restrict__ cnt) {
    int e = blockIdx.x * 256 + threadIdx.x;
    int sh = *mode;
    if (e < NE) {
        int d = ei[(size_t)(NE + e) << sh];
        atomicAdd(&cnt[d], 1);
    }
}

__global__ __launch_bounds__(256) void k_scan(const int* __restrict__ cnt, int* __restrict__ rowptr,
                                              int* __restrict__ cursor) {
    __shared__ int sums[256];
    const int chunk = (NN + 255) / 256;  // 196
    int t = threadIdx.x;
    int lo = t * chunk, hi = min(lo + chunk, NN);
    int s = 0;
    for (int i = lo; i < hi; ++i) s += cnt[i];
    sums[t] = s;
    __syncthreads();
    if (t == 0) {
        int run = 0;
        for (int i = 0; i < 256; ++i) { int v = sums[i]; sums[i] = run; run += v; }
        rowptr[NN] = run;
    }
    __syncthreads();
    int run = sums[t];
    for (int i = lo; i < hi; ++i) {
        rowptr[i] = run; cursor[i] = run; run += cnt[i];
    }
}

__global__ __launch_bounds__(256) void k_fill(const int* __restrict__ ei, const int* __restrict__ mode,
                                              int* __restrict__ cursor, int* __restrict__ srclist) {
    int e = blockIdx.x * 256 + threadIdx.x;
    int sh = *mode;
    if (e < NE) {
        int s = ei[(size_t)e << sh];
        int d = ei[(size_t)(NE + e) << sh];
        int p = atomicAdd(&cursor[d], 1);
        srclist[p] = s;
    }
}

// ---------------- x -> bf16 workspace copy (dtype-dispatched) ----------------
__global__ __launch_bounds__(256) void k_cvt(const void* __restrict__ x, const int* __restrict__ fmode,
                                             ushort_t* __restrict__ xb) {
    int i = blockIdx.x * 256 + threadIdx.x;
    const int total = NN * 128 / 4;
    if (i >= total) return;
    if (*fmode) {
        reinterpret_cast<ushort4*>(xb)[i] = reinterpret_cast<const ushort4*>(x)[i];
    } else {
        float4 v = reinterpret_cast<const float4*>(x)[i];
        ushort4 o;
        o.x = f2bf(v.x); o.y = f2bf(v.y); o.z = f2bf(v.z); o.w = f2bf(v.w);
        reinterpret_cast<ushort4*>(xb)[i] = o;
    }
}

// ---------------- weight/bias prep, NON-transposed concat ----------------
__global__ __launch_bounds__(256) void k_prep2(const void* __restrict__ W1l, const void* __restrict__ W1r,
                                               const void* __restrict__ W2l, const void* __restrict__ W2r,
                                               const void* __restrict__ Wd,
                                               const void* __restrict__ b1, const void* __restrict__ b2,
                                               const void* __restrict__ bd,
                                               const int* __restrict__ fmode,
                                               ushort_t* __restrict__ w1cat, ushort_t* __restrict__ w2cat,
                                               ushort_t* __restrict__ wdcat,
                                               float* __restrict__ b1f, float* __restrict__ b2f,
                                               float* __restrict__ bdf) {
    int idx = blockIdx.x * 256 + threadIdx.x;
    int bf = *fmode;
    if (idx < 65536) {
        float v = (idx < 32768) ? rdf(W1l, idx, bf) : rdf(W1r, idx - 32768, bf);
        w1cat[idx] = f2bf(v);
    } else if (idx < 98304) {
        int t = idx - 65536;
        float v = (t < 16384) ? rdf(W2l, t, bf) : rdf(W2r, t - 16384, bf);
        w2cat[t] = f2bf(v);
    } else if (idx < 106496) {
        int t = idx - 98304;
        wdcat[t] = f2bf(rdf(Wd, t, bf));
    } else if (idx < 106752) {
        b1f[idx - 106496] = rdf(b1, idx - 106496, bf);
    } else if (idx < 106816) {
        b2f[idx - 106752] = rdf(b2, idx - 106752, bf);
    } else if (idx < 106944) {
        bdf[idx - 106816] = rdf(bd, idx - 106816, bf);
    }
}

// ---------------- mean aggregation (gather via CSR, one wave per node) ----------------
__global__ __launch_bounds__(256) void k_agg128(const ushort_t* __restrict__ xb, const int* __restrict__ rowptr,
                                                const int* __restrict__ srclist, ushort_t* __restrict__ out) {
    int node = (blockIdx.x * 256 + threadIdx.x) >> 6;
    int lane = threadIdx.x & 63;
    if (node >= NN) return;
    int beg = rowptr[node], end = rowptr[node + 1];
    float a0 = 0.f, a1 = 0.f;
    for (int j = beg; j < end; ++j) {
        int s = srclist[j];
        uint32_t p = *reinterpret_cast<const uint32_t*>(xb + (size_t)s * 128 + lane * 2);
        a0 += bf2f((uint16_t)(p & 0xffff));
        a1 += bf2f((uint16_t)(p >> 16));
    }
    float inv = 1.0f / (float)max(end - beg, 1);
    uint32_t o = (uint32_t)f2bf(a0 * inv) | ((uint32_t)f2bf(a1 * inv) << 16);
    *reinterpret_cast<uint32_t*>(out + (size_t)node * 128 + lane * 2) = o;
}

__global__ __launch_bounds__(256) void k_agg256(const ushort_t* __restrict__ hsrc, const int* __restrict__ rowptr,
                                                const int* __restrict__ srclist, ushort_t* __restrict__ out) {
    int node = (blockIdx.x * 256 + threadIdx.x) >> 6;
    int lane = threadIdx.x & 63;
    if (node >= NN) return;
    int beg = rowptr[node], end = rowptr[node + 1];
    float a0 = 0.f, a1 = 0.f, a2 = 0.f, a3 = 0.f;
    for (int j = beg; j < end; ++j) {
        int s = srclist[j];
        uint2 p = *reinterpret_cast<const uint2*>(hsrc + (size_t)s * 256 + lane * 4);
        a0 += bf2f((uint16_t)(p.x & 0xffff));
        a1 += bf2f((uint16_t)(p.x >> 16));
        a2 += bf2f((uint16_t)(p.y & 0xffff));
        a3 += bf2f((uint16_t)(p.y >> 16));
    }
    float inv = 1.0f / (float)max(end - beg, 1);
    uint2 o;
    o.x = (uint32_t)f2bf(a0 * inv) | ((uint32_t)f2bf(a1 * inv) << 16);
    o.y = (uint32_t)f2bf(a2 * inv) | ((uint32_t)f2bf(a3 * inv) << 16);
    *reinterpret_cast<uint2*>(out + (size_t)node * 256 + lane * 4) = o;
}

// ---------------- GEMM1 (VALU, 4 nodes/block): h = relu([meanx|xb]@[W1l;W1r]+b1) ----------------
__global__ __launch_bounds__(256) void k_gemm1v(const ushort_t* __restrict__ meanx, const ushort_t* __restrict__ xb,
                                                const ushort_t* __restrict__ w1cat, const float* __restrict__ b1f,
                                                ushort_t* __restrict__ h) {
    __shared__ float a_sh[4][256];
    int node0 = blockIdx.x * 4;
    int t = threadIdx.x;
#pragma unroll
    for (int n = 0; n < 4; ++n) {
        a_sh[n][t] = (t < 128) ? bf2f(meanx[(size_t)(node0 + n) * 128 + t])
                               : bf2f(xb[(size_t)(node0 + n) * 128 + (t - 128)]);
    }
    __syncthreads();
    float acc0 = 0.f, acc1 = 0.f, acc2 = 0.f, acc3 = 0.f;
    for (int k = 0; k < 256; ++k) {
        float w = bf2f(w1cat[k * 256 + t]);
        acc0 += a_sh[0][k] * w;
        acc1 += a_sh[1][k] * w;
        acc2 += a_sh[2][k] * w;
        acc3 += a_sh[3][k] * w;
    }
    float bias = b1f[t];
    h[(size_t)(node0 + 0) * 256 + t] = f2bf(fmaxf(acc0 + bias, 0.f));
    h[(size_t)(node0 + 1) * 256 + t] = f2bf(fmaxf(acc1 + bias, 0.f));
    h[(size_t)(node0 + 2) * 256 + t] = f2bf(fmaxf(acc2 + bias, 0.f));
    h[(size_t)(node0 + 3) * 256 + t] = f2bf(fmaxf(acc3 + bias, 0.f));
}

// ---------------- GEMM2 (VALU, 4 nodes/block): z = [meanh|h]@[W2l;W2r]+b2 -> f32 out ----------------
__global__ __launch_bounds__(256) void k_gemm2v(const ushort_t* __restrict__ meanh, const ushort_t* __restrict__ h,
                                                const ushort_t* __restrict__ w2cat, const float* __restrict__ b2f,
                                                float* __restrict__ z) {
    __shared__ float a_sh[4][512];
    __shared__ float red[4][256];
    int node0 = blockIdx.x * 4;
    int t = threadIdx.x;
#pragma unroll
    for (int n = 0; n < 4; ++n) {
        a_sh[n][t]       = bf2f(meanh[(size_t)(node0 + n) * 256 + t]);
        a_sh[n][256 + t] = bf2f(h[(size_t)(node0 + n) * 256 + t]);
    }
    __syncthreads();
    int kc = t >> 6;          // 0..3, 128 k each
    int c  = t & 63;
    int k0 = kc * 128;
    float acc0 = 0.f, acc1 = 0.f, acc2 = 0.f, acc3 = 0.f;
    for (int k = k0; k < k0 + 128; ++k) {
        float w = bf2f(w2cat[k * 64 + c]);
        acc0 += a_sh[0][k] * w;
        acc1 += a_sh[1][k] * w;
        acc2 += a_sh[2][k] * w;
        acc3 += a_sh[3][k] * w;
    }
    red[0][t] = acc0; red[1][t] = acc1; red[2][t] = acc2; red[3][t] = acc3;
    __syncthreads();
    if (t < 64) {
#pragma unroll
        for (int n = 0; n < 4; ++n) {
            float v = red[n][t] + red[n][64 + t] + red[n][128 + t] + red[n][192 + t] + b2f[t];
            z[(size_t)(node0 + n) * 64 + t] = v;
        }
    }
}

// ---------------- GEMM3 (VALU, 4 nodes/block): x_hat = z @ Wd + bd -> f32 out ----------------
__global__ __launch_bounds__(256) void k_gemm3v(const float* __restrict__ z, const ushort_t* __restrict__ wdcat,
                                                const float* __restrict__ bdf, float* __restrict__ xhat) {
    __shared__ float zsh[4][64];
    __shared__ float red[4][256];
    int node0 = blockIdx.x * 4;
    int t = threadIdx.x;
    if (t < 256) {
        int n = t >> 6, j = t & 63;
        zsh[n][j] = z[(size_t)(node0 + n) * 64 + j];
    }
    __syncthreads();
    int kc = t >> 7;          // 0..1, 32 k each
    int c  = t & 127;
    int k0 = kc * 32;
    float acc0 = 0.f, acc1 = 0.f, acc2 = 0.f, acc3 = 0.f;
    for (int k = k0; k < k0 + 32; ++k) {
        float w = bf2f(wdcat[k * 128 + c]);
        acc0 += zsh[0][k] * w;
        acc1 += zsh[1][k] * w;
        acc2 += zsh[2][k] * w;
        acc3 += zsh[3][k] * w;
    }
    red[0][t] = acc0; red[1][t] = acc1; red[2][t] = acc2; red[3][t] = acc3;
    __syncthreads();
    if (t < 128) {
#pragma unroll
        for (int n = 0; n < 4; ++n) {
            float v = red[n][t] + red[n][128 + t] + bdf[t];
            xhat[(size_t)(node0 + n) * 128 + t] = v;
        }
    }
}

extern "C" void kernel_launch(void* const* d_in, const int* in_sizes, int n_in,
                              void* d_out, int out_size, void* d_ws, size_t ws_size,
                              hipStream_t stream) {
    // ---- order-agnostic input identification by element count ----
    const void *px = nullptr, *pei = nullptr, *pW1l = nullptr, *pW1r = nullptr,
               *pW2l = nullptr, *pW2r = nullptr, *pWd = nullptr,
               *pb1 = nullptr, *pb2 = nullptr, *pbd = nullptr;
    for (int i = 0; i < n_in; ++i) {
        const void* p = d_in[i];
        switch (in_sizes[i]) {
            case 6400000: px  = p; break;
            case 1600000: pei = p; break;
            case 32768:   if (!pW1l) pW1l = p; else pW1r = p; break;
            case 16384:   if (!pW2l) pW2l = p; else pW2r = p; break;
            case 8192:    pWd = p; break;
            case 256:     pb1 = p; break;
            case 128:     pbd = p; break;
            case 64:      pb2 = p; break;
            default: break;
        }
    }
    if (!px || !pei || !pW1l || !pW1r || !pW2l || !pW2r || !pWd || !pb1 || !pb2 || !pbd) {
        px = d_in[0]; pei = d_in[1]; pW1l = d_in[2]; pb1 = d_in[3]; pW1r = d_in[4];
        pW2l = d_in[5]; pb2 = d_in[6]; pW2r = d_in[7]; pWd = d_in[8]; pbd = d_in[9];
    }
    const int* ei = (const int*)pei;

    // ---- workspace (~42.4 MB) ----
    char* base = (char*)d_ws;
    size_t off = 0;
    auto alloc = [&](size_t bytes) -> void* {
        void* r = base + off;
        off = (off + bytes + 255) & ~(size_t)255;
        return r;
    };
    int* mode     = (int*)alloc(4);
    int* fmode    = (int*)alloc(4);
    int* cnt      = (int*)alloc((size_t)NN * 4);
    int* rowptr   = (int*)alloc((size_t)(NN + 1) * 4);
    int* cursor   = (int*)alloc((size_t)NN * 4);
    int* srclist  = (int*)alloc((size_t)NE * 4);
    ushort_t* w1cat = (ushort_t*)alloc((size_t)65536 * 2);
    ushort_t* w2cat = (ushort_t*)alloc((size_t)32768 * 2);
    ushort_t* wdcat = (ushort_t*)alloc((size_t)8192 * 2);
    float* b1f    = (float*)alloc(256 * 4);
    float* b2f    = (float*)alloc(64 * 4);
    float* bdf    = (float*)alloc(128 * 4);
    ushort_t* xb  = (ushort_t*)alloc((size_t)NN * 128 * 2);
    ushort_t* h   = (ushort_t*)alloc((size_t)NN * 256 * 2);

    // ---- outputs are FLOAT32: d_out = z[NN,64] f32 then x_hat[NN,128] f32 (38.4MB) ----
    float* out_z    = (float*)d_out;
    float* out_xhat = out_z + (size_t)NN * 64;

    // scratch aliases inside d_out (dead before their regions are finalized):
    ushort_t* meanx = (ushort_t*)out_z;      // [NN,128] bf16 = 12.8MB in z region (z written later by gemm2)
    ushort_t* meanh = (ushort_t*)out_xhat;   // [NN,256] bf16 = 25.6MB in x_hat region (x_hat written later by gemm3)

    hipMemsetAsync(cnt, 0, (size_t)NN * 4, stream);

    k_detect<<<1, 256, 0, stream>>>(ei, mode);
    k_dtypef<<<1, 256, 0, stream>>>((const ushort_t*)px, fmode);

    int eb = (NE + 255) / 256;
    k_degree<<<eb, 256, 0, stream>>>(ei, mode, cnt);
    k_scan<<<1, 256, 0, stream>>>(cnt, rowptr, cursor);
    k_fill<<<eb, 256, 0, stream>>>(ei, mode, cursor, srclist);

    k_cvt<<<(NN * 128 / 4 + 255) / 256, 256, 0, stream>>>(px, fmode, xb);
    k_prep2<<<418, 256, 0, stream>>>(pW1l, pW1r, pW2l, pW2r, pWd, pb1, pb2, pbd, fmode,
                                     w1cat, w2cat, wdcat, b1f, b2f, bdf);

    int ab = (NN + 3) / 4;                     // 12500 blocks, 4 waves each
    k_agg128<<<ab, 256, 0, stream>>>(xb, rowptr, srclist, meanx);

    k_gemm1v<<<NN / 4, 256, 0, stream>>>(meanx, xb, w1cat, b1f, h);
    k_agg256<<<ab, 256, 0, stream>>>(h, rowptr, srclist, meanh);
    k_gemm2v<<<NN / 4, 256, 0, stream>>>(meanh, h, w2cat, b2f, out_z);
    k_gemm3v<<<NN / 4, 256, 0, stream>>>(out_z, wdcat, bdf, out_xhat);
}

// Round 8
// 495.562 us; speedup vs baseline: 1.5529x; 1.5529x over previous
//
#include <hip/hip_runtime.h>
#include <stdint.h>

#define NN 50000
#define NE 800000
// IN=128, HID=256, LAT=64

typedef __bf16 bf16x8 __attribute__((ext_vector_type(8)));
typedef float f32x4 __attribute__((ext_vector_type(4)));
typedef unsigned short ushort_t;

__device__ inline float bf2f(uint16_t u) {
    union { uint32_t i; float f; } v; v.i = ((uint32_t)u) << 16; return v.f;
}
__device__ inline uint16_t f2bf(float f) {
    uint32_t u = __float_as_uint(f);
    u += 0x7fffu + ((u >> 16) & 1u);
    return (uint16_t)(u >> 16);
}
__device__ inline float rdf(const void* p, int i, int bf) {
    return bf ? bf2f(((const ushort_t*)p)[i]) : ((const float*)p)[i];
}

// ---------------- edge dtype detection (int64 vs int32 storage) ----------------
__global__ __launch_bounds__(256) void k_detect(const int* __restrict__ ei, int* __restrict__ mode) {
    __shared__ int nz;
    if (threadIdx.x == 0) nz = 0;
    __syncthreads();
    int t = threadIdx.x;
    int v = ei[2 * t + 1] | ei[2 * (t + 256) + 1] | ei[2 * (t + 512) + 1] | ei[2 * (t + 768) + 1];
    if (v) atomicOr(&nz, 1);
    __syncthreads();
    if (t == 0) *mode = (nz == 0) ? 1 : 0;
}

// ---------------- float dtype detection (f32 vs bf16 storage) ----------------
__global__ __launch_bounds__(256) void k_dtypef(const ushort_t* __restrict__ xw, int* __restrict__ fmode) {
    __shared__ int bad;
    if (threadIdx.x == 0) bad = 0;
    __syncthreads();
    int t = threadIdx.x;
#pragma unroll
    for (int r = 0; r < 2; ++r) {
        uint16_t w = xw[t + 256 * r];
        int e = (w >> 7) & 0xFF;
        if (!(w == 0 || (e >= 96 && e <= 144))) atomicOr(&bad, 1);
    }
    __syncthreads();
    if (t == 0) *fmode = (bad == 0) ? 1 : 0;
}

// ---------------- CSR build ----------------
__global__ __launch_bounds__(256) void k_degree(const int* __restrict__ ei, const int* __restrict__ mode,
                                                int* __restrict__ cnt) {
    int e = blockIdx.x * 256 + threadIdx.x;
    int sh = *mode;
    if (e < NE) {
        int d = ei[(size_t)(NE + e) << sh];
        atomicAdd(&cnt[d], 1);
    }
}

__global__ __launch_bounds__(256) void k_scan(const int* __restrict__ cnt, int* __restrict__ rowptr,
                                              int* __restrict__ cursor) {
    __shared__ int sums[256];
    const int chunk = (NN + 255) / 256;
    int t = threadIdx.x;
    int lo = t * chunk, hi = min(lo + chunk, NN);
    int s = 0;
    for (int i = lo; i < hi; ++i) s += cnt[i];
    sums[t] = s;
    __syncthreads();
    if (t == 0) {
        int run = 0;
        for (int i = 0; i < 256; ++i) { int v = sums[i]; sums[i] = run; run += v; }
        rowptr[NN] = run;
    }
    __syncthreads();
    int run = sums[t];
    for (int i = lo; i < hi; ++i) {
        rowptr[i] = run; cursor[i] = run; run += cnt[i];
    }
}

__global__ __launch_bounds__(256) void k_fill(const int* __restrict__ ei, const int* __restrict__ mode,
                                              int* __restrict__ cursor, int* __restrict__ srclist) {
    int e = blockIdx.x * 256 + threadIdx.x;
    int sh = *mode;
    if (e < NE) {
        int s = ei[(size_t)e << sh];
        int d = ei[(size_t)(NE + e) << sh];
        int p = atomicAdd(&cursor[d], 1);
        srclist[p] = s;
    }
}

// ---------------- x -> bf16 workspace copy ----------------
__global__ __launch_bounds__(256) void k_cvt(const void* __restrict__ x, const int* __restrict__ fmode,
                                             ushort_t* __restrict__ xb) {
    int i = blockIdx.x * 256 + threadIdx.x;
    const int total = NN * 128 / 4;
    if (i >= total) return;
    if (*fmode) {
        reinterpret_cast<ushort4*>(xb)[i] = reinterpret_cast<const ushort4*>(x)[i];
    } else {
        float4 v = reinterpret_cast<const float4*>(x)[i];
        ushort4 o;
        o.x = f2bf(v.x); o.y = f2bf(v.y); o.z = f2bf(v.z); o.w = f2bf(v.w);
        reinterpret_cast<ushort4*>(xb)[i] = o;
    }
}

// ---------------- weight prep: transposed bf16 for MFMA B-operand ----------------
// wt   [256c][256k]: k<128 -> W1l[k][c], else W1r[k-128][c]
// w2lt [64c][256k]  = W2l[k][c];  w2rt [64c][256k] = W2r[k][c]
// wdt  [128c][64k]  = Wd[k][c]
__global__ __launch_bounds__(256) void k_prep3(const void* __restrict__ W1l, const void* __restrict__ W1r,
                                               const void* __restrict__ W2l, const void* __restrict__ W2r,
                                               const void* __restrict__ Wd,
                                               const void* __restrict__ b1, const void* __restrict__ b2,
                                               const void* __restrict__ bd,
                                               const int* __restrict__ fmode,
                                               ushort_t* __restrict__ wt, ushort_t* __restrict__ w2lt,
                                               ushort_t* __restrict__ w2rt, ushort_t* __restrict__ wdt,
                                               float* __restrict__ b1f, float* __restrict__ b2f,
                                               float* __restrict__ bdf) {
    int idx = blockIdx.x * 256 + threadIdx.x;
    int bf = *fmode;
    if (idx < 65536) {
        int c = idx >> 8, k = idx & 255;
        float v = (k < 128) ? rdf(W1l, k * 256 + c, bf) : rdf(W1r, (k - 128) * 256 + c, bf);
        wt[c * 256 + k] = f2bf(v);
    } else if (idx < 81920) {
        int t = idx - 65536;
        int c = t >> 8, k = t & 255;
        w2lt[c * 256 + k] = f2bf(rdf(W2l, k * 64 + c, bf));
    } else if (idx < 98304) {
        int t = idx - 81920;
        int c = t >> 8, k = t & 255;
        w2rt[c * 256 + k] = f2bf(rdf(W2r, k * 64 + c, bf));
    } else if (idx < 106496) {
        int t = idx - 98304;
        int c = t >> 6, k = t & 63;
        wdt[c * 64 + k] = f2bf(rdf(Wd, k * 128 + c, bf));
    } else if (idx < 106752) {
        b1f[idx - 106496] = rdf(b1, idx - 106496, bf);
    } else if (idx < 106816) {
        b2f[idx - 106752] = rdf(b2, idx - 106752, bf);
    } else if (idx < 106944) {
        bdf[idx - 106816] = rdf(bd, idx - 106816, bf);
    }
}

// ---------------- agg1: meanx = mean of x rows (one wave/node, 4-way edge unroll) ----------------
__global__ __launch_bounds__(256) void k_agg128(const ushort_t* __restrict__ xb, const int* __restrict__ rowptr,
                                                const int* __restrict__ srclist, ushort_t* __restrict__ out) {
    int node = (blockIdx.x * 256 + threadIdx.x) >> 6;
    int lane = threadIdx.x & 63;
    if (node >= NN) return;
    int beg = rowptr[node], end = rowptr[node + 1];
    float a0 = 0.f, a1 = 0.f;
    int j = beg;
    for (; j + 3 < end; j += 4) {
        int s0 = srclist[j], s1 = srclist[j + 1], s2 = srclist[j + 2], s3 = srclist[j + 3];
        uint32_t p0 = *reinterpret_cast<const uint32_t*>(xb + (size_t)s0 * 128 + lane * 2);
        uint32_t p1 = *reinterpret_cast<const uint32_t*>(xb + (size_t)s1 * 128 + lane * 2);
        uint32_t p2 = *reinterpret_cast<const uint32_t*>(xb + (size_t)s2 * 128 + lane * 2);
        uint32_t p3 = *reinterpret_cast<const uint32_t*>(xb + (size_t)s3 * 128 + lane * 2);
        a0 += bf2f((uint16_t)(p0 & 0xffff)) + bf2f((uint16_t)(p1 & 0xffff))
            + bf2f((uint16_t)(p2 & 0xffff)) + bf2f((uint16_t)(p3 & 0xffff));
        a1 += bf2f((uint16_t)(p0 >> 16)) + bf2f((uint16_t)(p1 >> 16))
            + bf2f((uint16_t)(p2 >> 16)) + bf2f((uint16_t)(p3 >> 16));
    }
    for (; j < end; ++j) {
        int s = srclist[j];
        uint32_t p = *reinterpret_cast<const uint32_t*>(xb + (size_t)s * 128 + lane * 2);
        a0 += bf2f((uint16_t)(p & 0xffff));
        a1 += bf2f((uint16_t)(p >> 16));
    }
    float inv = 1.0f / (float)max(end - beg, 1);
    uint32_t o = (uint32_t)f2bf(a0 * inv) | ((uint32_t)f2bf(a1 * inv) << 16);
    *reinterpret_cast<uint32_t*>(out + (size_t)node * 128 + lane * 2) = o;
}

// ---------------- GEMM1 (MFMA): h = relu([meanx|xb] @ wt^T + b1), 16 rows/block ----------------
__global__ __launch_bounds__(256) void k_gemm1(const ushort_t* __restrict__ meanx, const ushort_t* __restrict__ xb,
                                               const ushort_t* __restrict__ wt, const float* __restrict__ b1f,
                                               ushort_t* __restrict__ h) {
    int wv = threadIdx.x >> 6, lane = threadIdx.x & 63;
    int m = lane & 15, q = lane >> 4;
    int r0 = blockIdx.x * 16;
    int row = r0 + m;
    f32x4 acc0 = {0.f, 0.f, 0.f, 0.f}, acc1 = acc0, acc2 = acc0, acc3 = acc0;
#pragma unroll
    for (int ks = 0; ks < 8; ++ks) {
        int kb = ks * 32 + q * 8;
        const ushort_t* ap = (kb < 128) ? (meanx + (size_t)row * 128 + kb)
                                        : (xb + (size_t)row * 128 + (kb - 128));
        bf16x8 a = *reinterpret_cast<const bf16x8*>(ap);
        const ushort_t* wb = wt + (size_t)(wv * 64 + m) * 256 + kb;
        bf16x8 b0 = *reinterpret_cast<const bf16x8*>(wb);
        bf16x8 b1v = *reinterpret_cast<const bf16x8*>(wb + 16 * 256);
        bf16x8 b2v = *reinterpret_cast<const bf16x8*>(wb + 32 * 256);
        bf16x8 b3v = *reinterpret_cast<const bf16x8*>(wb + 48 * 256);
        acc0 = __builtin_amdgcn_mfma_f32_16x16x32_bf16(a, b0, acc0, 0, 0, 0);
        acc1 = __builtin_amdgcn_mfma_f32_16x16x32_bf16(a, b1v, acc1, 0, 0, 0);
        acc2 = __builtin_amdgcn_mfma_f32_16x16x32_bf16(a, b2v, acc2, 0, 0, 0);
        acc3 = __builtin_amdgcn_mfma_f32_16x16x32_bf16(a, b3v, acc3, 0, 0, 0);
    }
    f32x4 accs[4] = {acc0, acc1, acc2, acc3};
#pragma unroll
    for (int ct = 0; ct < 4; ++ct) {
        int c = wv * 64 + ct * 16 + m;
        float bias = b1f[c];
#pragma unroll
        for (int i = 0; i < 4; ++i) {
            int rr = r0 + q * 4 + i;
            h[(size_t)rr * 256 + c] = f2bf(fmaxf(accs[ct][i] + bias, 0.f));
        }
    }
}

// ---------------- GEMM2a (MFMA): y = h@W2l (bf16), r = h@W2r + b2 (f32), 16 rows/block ----------------
// waves 0,1 -> y cols (wv&1)*32..+31 ; waves 2,3 -> r cols likewise
__global__ __launch_bounds__(256) void k_gemm2a(const ushort_t* __restrict__ h,
                                                const ushort_t* __restrict__ w2lt, const ushort_t* __restrict__ w2rt,
                                                const float* __restrict__ b2f,
                                                ushort_t* __restrict__ y, float* __restrict__ r) {
    int wv = threadIdx.x >> 6, lane = threadIdx.x & 63;
    int m = lane & 15, q = lane >> 4;
    int r0 = blockIdx.x * 16;
    int row = r0 + m;
    int op = wv >> 1;                   // 0 = y (W2l), 1 = r (W2r)
    int cb = (wv & 1) * 32;             // column base within 64
    const ushort_t* wtx = op ? w2rt : w2lt;
    f32x4 acc0 = {0.f, 0.f, 0.f, 0.f}, acc1 = acc0;
#pragma unroll
    for (int ks = 0; ks < 8; ++ks) {
        int kb = ks * 32 + q * 8;
        bf16x8 a = *reinterpret_cast<const bf16x8*>(h + (size_t)row * 256 + kb);
        const ushort_t* wb = wtx + (size_t)(cb + m) * 256 + kb;
        bf16x8 b0 = *reinterpret_cast<const bf16x8*>(wb);
        bf16x8 b1v = *reinterpret_cast<const bf16x8*>(wb + 16 * 256);
        acc0 = __builtin_amdgcn_mfma_f32_16x16x32_bf16(a, b0, acc0, 0, 0, 0);
        acc1 = __builtin_amdgcn_mfma_f32_16x16x32_bf16(a, b1v, acc1, 0, 0, 0);
    }
    f32x4 accs[2] = {acc0, acc1};
#pragma unroll
    for (int ct = 0; ct < 2; ++ct) {
        int c = cb + ct * 16 + m;
#pragma unroll
        for (int i = 0; i < 4; ++i) {
            int rr = r0 + q * 4 + i;
            if (op == 0) {
                y[(size_t)rr * 64 + c] = f2bf(accs[ct][i]);
            } else {
                r[(size_t)rr * 64 + c] = accs[ct][i] + b2f[c];
            }
        }
    }
}

// ---------------- agg2y: z = mean(y over neighbors) + r ; write z f32 (out) + bf16 (zb) ----------------
// one wave/node; half-wave handles alternating edges (2 edges in flight); lane&31 -> dim pair
__global__ __launch_bounds__(256) void k_agg2y(const ushort_t* __restrict__ y, const int* __restrict__ rowptr,
                                               const int* __restrict__ srclist, const float* __restrict__ r,
                                               float* __restrict__ zf, ushort_t* __restrict__ zb) {
    int node = (blockIdx.x * 256 + threadIdx.x) >> 6;
    int lane = threadIdx.x & 63;
    if (node >= NN) return;
    int half = lane >> 5, l32 = lane & 31;
    int beg = rowptr[node], end = rowptr[node + 1];
    float a0 = 0.f, a1 = 0.f;
    int j = beg + half;
    for (; j + 2 < end; j += 4) {
        int s0 = srclist[j], s1 = srclist[j + 2];
        uint32_t p0 = *reinterpret_cast<const uint32_t*>(y + (size_t)s0 * 64 + l32 * 2);
        uint32_t p1 = *reinterpret_cast<const uint32_t*>(y + (size_t)s1 * 64 + l32 * 2);
        a0 += bf2f((uint16_t)(p0 & 0xffff)) + bf2f((uint16_t)(p1 & 0xffff));
        a1 += bf2f((uint16_t)(p0 >> 16)) + bf2f((uint16_t)(p1 >> 16));
    }
    for (; j < end; j += 2) {
        int s = srclist[j];
        uint32_t p = *reinterpret_cast<const uint32_t*>(y + (size_t)s * 64 + l32 * 2);
        a0 += bf2f((uint16_t)(p & 0xffff));
        a1 += bf2f((uint16_t)(p >> 16));
    }
    a0 += __shfl_xor(a0, 32);
    a1 += __shfl_xor(a1, 32);
    if (half == 0) {
        float inv = 1.0f / (float)max(end - beg, 1);
        float2 rv = *reinterpret_cast<const float2*>(r + (size_t)node * 64 + l32 * 2);
        float z0 = a0 * inv + rv.x;
        float z1 = a1 * inv + rv.y;
        float2 zo; zo.x = z0; zo.y = z1;
        *reinterpret_cast<float2*>(zf + (size_t)node * 64 + l32 * 2) = zo;
        uint32_t o = (uint32_t)f2bf(z0) | ((uint32_t)f2bf(z1) << 16);
        *reinterpret_cast<uint32_t*>(zb + (size_t)node * 64 + l32 * 2) = o;
    }
}

// ---------------- GEMM3 (MFMA): x_hat = zb @ wdt^T + bd -> f32, 16 rows/block ----------------
__global__ __launch_bounds__(256) void k_gemm3(const ushort_t* __restrict__ zb, const ushort_t* __restrict__ wdt,
                                               const float* __restrict__ bdf, float* __restrict__ xhat) {
    int wv = threadIdx.x >> 6, lane = threadIdx.x & 63;
    int m = lane & 15, q = lane >> 4;
    int r0 = blockIdx.x * 16;
    int row = r0 + m;
    f32x4 acc0 = {0.f, 0.f, 0.f, 0.f}, acc1 = acc0;
#pragma unroll
    for (int ks = 0; ks < 2; ++ks) {
        int kb = ks * 32 + q * 8;
        bf16x8 a = *reinterpret_cast<const bf16x8*>(zb + (size_t)row * 64 + kb);
        const ushort_t* wb = wdt + (size_t)(wv * 32 + m) * 64 + kb;
        bf16x8 b0 = *reinterpret_cast<const bf16x8*>(wb);
        bf16x8 b1v = *reinterpret_cast<const bf16x8*>(wb + 16 * 64);
        acc0 = __builtin_amdgcn_mfma_f32_16x16x32_bf16(a, b0, acc0, 0, 0, 0);
        acc1 = __builtin_amdgcn_mfma_f32_16x16x32_bf16(a, b1v, acc1, 0, 0, 0);
    }
    f32x4 accs[2] = {acc0, acc1};
#pragma unroll
    for (int ct = 0; ct < 2; ++ct) {
        int c = wv * 32 + ct * 16 + m;
        float bias = bdf[c];
#pragma unroll
        for (int i = 0; i < 4; ++i) {
            int rr = r0 + q * 4 + i;
            xhat[(size_t)rr * 128 + c] = accs[ct][i] + bias;
        }
    }
}

extern "C" void kernel_launch(void* const* d_in, const int* in_sizes, int n_in,
                              void* d_out, int out_size, void* d_ws, size_t ws_size,
                              hipStream_t stream) {
    // ---- order-agnostic input identification by element count ----
    const void *px = nullptr, *pei = nullptr, *pW1l = nullptr, *pW1r = nullptr,
               *pW2l = nullptr, *pW2r = nullptr, *pWd = nullptr,
               *pb1 = nullptr, *pb2 = nullptr, *pbd = nullptr;
    for (int i = 0; i < n_in; ++i) {
        const void* p = d_in[i];
        switch (in_sizes[i]) {
            case 6400000: px  = p; break;
            case 1600000: pei = p; break;
            case 32768:   if (!pW1l) pW1l = p; else pW1r = p; break;
            case 16384:   if (!pW2l) pW2l = p; else pW2r = p; break;
            case 8192:    pWd = p; break;
            case 256:     pb1 = p; break;
            case 128:     pbd = p; break;
            case 64:      pb2 = p; break;
            default: break;
        }
    }
    if (!px || !pei || !pW1l || !pW1r || !pW2l || !pW2r || !pWd || !pb1 || !pb2 || !pbd) {
        px = d_in[0]; pei = d_in[1]; pW1l = d_in[2]; pb1 = d_in[3]; pW1r = d_in[4];
        pW2l = d_in[5]; pb2 = d_in[6]; pW2r = d_in[7]; pWd = d_in[8]; pbd = d_in[9];
    }
    const int* ei = (const int*)pei;

    // ---- workspace (~42.5 MB) ----
    char* base = (char*)d_ws;
    size_t off = 0;
    auto alloc = [&](size_t bytes) -> void* {
        void* r = base + off;
        off = (off + bytes + 255) & ~(size_t)255;
        return r;
    };
    int* mode     = (int*)alloc(4);
    int* fmode    = (int*)alloc(4);
    int* cnt      = (int*)alloc((size_t)NN * 4);
    int* rowptr   = (int*)alloc((size_t)(NN + 1) * 4);
    int* cursor   = (int*)alloc((size_t)NN * 4);
    int* srclist  = (int*)alloc((size_t)NE * 4);
    ushort_t* wt   = (ushort_t*)alloc((size_t)65536 * 2);
    ushort_t* w2lt = (ushort_t*)alloc((size_t)16384 * 2);
    ushort_t* w2rt = (ushort_t*)alloc((size_t)16384 * 2);
    ushort_t* wdt  = (ushort_t*)alloc((size_t)8192 * 2);
    float* b1f    = (float*)alloc(256 * 4);
    float* b2f    = (float*)alloc(64 * 4);
    float* bdf    = (float*)alloc(128 * 4);
    ushort_t* xb  = (ushort_t*)alloc((size_t)NN * 128 * 2);   // dead after gemm1
    ushort_t* h   = (ushort_t*)alloc((size_t)NN * 256 * 2);

    // outputs f32: z [NN,64] then x_hat [NN,128]
    float* out_z    = (float*)d_out;
    float* out_xhat = out_z + (size_t)NN * 64;

    // aliases:
    ushort_t* meanx = (ushort_t*)out_xhat;                       // [NN,128] bf16, dead after gemm1
    float*    rbuf  = (float*)((char*)out_xhat + (size_t)NN * 128 * 2); // [NN,64] f32, dead before gemm3
    ushort_t* y     = xb;                                        // [NN,64] bf16 (xb dead after gemm1)
    ushort_t* zb    = xb + (size_t)NN * 64;                      // [NN,64] bf16

    hipMemsetAsync(cnt, 0, (size_t)NN * 4, stream);

    k_detect<<<1, 256, 0, stream>>>(ei, mode);
    k_dtypef<<<1, 256, 0, stream>>>((const ushort_t*)px, fmode);

    int eb = (NE + 255) / 256;
    k_degree<<<eb, 256, 0, stream>>>(ei, mode, cnt);
    k_scan<<<1, 256, 0, stream>>>(cnt, rowptr, cursor);
    k_fill<<<eb, 256, 0, stream>>>(ei, mode, cursor, srclist);

    k_cvt<<<(NN * 128 / 4 + 255) / 256, 256, 0, stream>>>(px, fmode, xb);
    k_prep3<<<418, 256, 0, stream>>>(pW1l, pW1r, pW2l, pW2r, pWd, pb1, pb2, pbd, fmode,
                                     wt, w2lt, w2rt, wdt, b1f, b2f, bdf);

    int ab = (NN + 3) / 4;                     // 12500 blocks, 4 waves each
    k_agg128<<<ab, 256, 0, stream>>>(xb, rowptr, srclist, meanx);

    int gb = NN / 16;                          // 3125
    k_gemm1<<<gb, 256, 0, stream>>>(meanx, xb, wt, b1f, h);
    k_gemm2a<<<gb, 256, 0, stream>>>(h, w2lt, w2rt, b2f, y, rbuf);
    k_agg2y<<<ab, 256, 0, stream>>>(y, rowptr, srclist, rbuf, out_z, zb);
    k_gemm3<<<gb, 256, 0, stream>>>(zb, wdt, bdf, out_xhat);
}

// Round 9
// 383.336 us; speedup vs baseline: 2.0076x; 1.2928x over previous
//
#include <hip/hip_runtime.h>
#include <stdint.h>

#define NN 50000
#define NE 800000
#define NB 196   // (NN+255)/256
// IN=128, HID=256, LAT=64

typedef __bf16 bf16x8 __attribute__((ext_vector_type(8)));
typedef float f32x4 __attribute__((ext_vector_type(4)));
typedef unsigned short ushort_t;

__device__ inline float bf2f(uint16_t u) {
    union { uint32_t i; float f; } v; v.i = ((uint32_t)u) << 16; return v.f;
}
__device__ inline uint16_t f2bf(float f) {
    uint32_t u = __float_as_uint(f);
    u += 0x7fffu + ((u >> 16) & 1u);
    return (uint16_t)(u >> 16);
}
__device__ inline float rdf(const void* p, int i, int bf) {
    return bf ? bf2f(((const ushort_t*)p)[i]) : ((const float*)p)[i];
}

// ---------------- edge dtype detection (int64 vs int32 storage) ----------------
__global__ __launch_bounds__(256) void k_detect(const int* __restrict__ ei, int* __restrict__ mode) {
    __shared__ int nz;
    if (threadIdx.x == 0) nz = 0;
    __syncthreads();
    int t = threadIdx.x;
    int v = ei[2 * t + 1] | ei[2 * (t + 256) + 1] | ei[2 * (t + 512) + 1] | ei[2 * (t + 768) + 1];
    if (v) atomicOr(&nz, 1);
    __syncthreads();
    if (t == 0) *mode = (nz == 0) ? 1 : 0;
}

// ---------------- float dtype detection (f32 vs bf16 storage) ----------------
__global__ __launch_bounds__(256) void k_dtypef(const ushort_t* __restrict__ xw, int* __restrict__ fmode) {
    __shared__ int bad;
    if (threadIdx.x == 0) bad = 0;
    __syncthreads();
    int t = threadIdx.x;
#pragma unroll
    for (int r = 0; r < 2; ++r) {
        uint16_t w = xw[t + 256 * r];
        int e = (w >> 7) & 0xFF;
        if (!(w == 0 || (e >= 96 && e <= 144))) atomicOr(&bad, 1);
    }
    __syncthreads();
    if (t == 0) *fmode = (bad == 0) ? 1 : 0;
}

// ---------------- CSR build ----------------
__global__ __launch_bounds__(256) void k_degree(const int* __restrict__ ei, const int* __restrict__ mode,
                                                int* __restrict__ cnt) {
    int e = blockIdx.x * 256 + threadIdx.x;
    int sh = *mode;
    if (e < NE) {
        int d = ei[(size_t)(NE + e) << sh];
        atomicAdd(&cnt[d], 1);
    }
}

// ---- 3-phase parallel exclusive scan of cnt[NN] -> rowptr/cursor ----
__device__ inline int block_scan256(int v, int* ws, int* btot) {
    int lane = threadIdx.x & 63, wv = threadIdx.x >> 6;
    int incl = v;
#pragma unroll
    for (int d = 1; d < 64; d <<= 1) {
        int n = __shfl_up(incl, d);
        if (lane >= d) incl += n;
    }
    if (lane == 63) ws[wv] = incl;
    __syncthreads();
    if (threadIdx.x == 0) {
        int r = 0;
#pragma unroll
        for (int k = 0; k < 4; ++k) { int t = ws[k]; ws[k] = r; r += t; }
        *btot = r;
    }
    __syncthreads();
    return ws[wv] + incl - v;   // exclusive prefix within block
}

__global__ __launch_bounds__(256) void k_scanA(const int* __restrict__ cnt, int* __restrict__ rowptr,
                                               int* __restrict__ blocksum) {
    __shared__ int ws[4];
    __shared__ int btot;
    int i = blockIdx.x * 256 + threadIdx.x;
    int v = (i < NN) ? cnt[i] : 0;
    int excl = block_scan256(v, ws, &btot);
    if (i < NN) rowptr[i] = excl;
    if (threadIdx.x == 0) blocksum[blockIdx.x] = btot;
}

__global__ __launch_bounds__(256) void k_scanB(const int* __restrict__ blocksum, int* __restrict__ blockoff,
                                               int* __restrict__ rowptr) {
    __shared__ int ws[4];
    __shared__ int btot;
    int t = threadIdx.x;
    int v = (t < NB) ? blocksum[t] : 0;
    int excl = block_scan256(v, ws, &btot);
    if (t < NB) blockoff[t] = excl;
    if (t == NB - 1) rowptr[NN] = excl + v;
}

__global__ __launch_bounds__(256) void k_scanC(int* __restrict__ rowptr, const int* __restrict__ blockoff,
                                               int* __restrict__ cursor) {
    int i = blockIdx.x * 256 + threadIdx.x;
    if (i < NN) {
        int v = rowptr[i] + blockoff[blockIdx.x];
        rowptr[i] = v;
        cursor[i] = v;
    }
}

__global__ __launch_bounds__(256) void k_fill(const int* __restrict__ ei, const int* __restrict__ mode,
                                              int* __restrict__ cursor, int* __restrict__ srclist) {
    int e = blockIdx.x * 256 + threadIdx.x;
    int sh = *mode;
    if (e < NE) {
        int s = ei[(size_t)e << sh];
        int d = ei[(size_t)(NE + e) << sh];
        int p = atomicAdd(&cursor[d], 1);
        srclist[p] = s;
    }
}

// ---------------- x -> bf16 workspace copy ----------------
__global__ __launch_bounds__(256) void k_cvt(const void* __restrict__ x, const int* __restrict__ fmode,
                                             ushort_t* __restrict__ xb) {
    int i = blockIdx.x * 256 + threadIdx.x;
    const int total = NN * 128 / 4;
    if (i >= total) return;
    if (*fmode) {
        reinterpret_cast<ushort4*>(xb)[i] = reinterpret_cast<const ushort4*>(x)[i];
    } else {
        float4 v = reinterpret_cast<const float4*>(x)[i];
        ushort4 o;
        o.x = f2bf(v.x); o.y = f2bf(v.y); o.z = f2bf(v.z); o.w = f2bf(v.w);
        reinterpret_cast<ushort4*>(xb)[i] = o;
    }
}

// ---------------- weight prep: transposed bf16 for MFMA B-operand ----------------
__global__ __launch_bounds__(256) void k_prep3(const void* __restrict__ W1l, const void* __restrict__ W1r,
                                               const void* __restrict__ W2l, const void* __restrict__ W2r,
                                               const void* __restrict__ Wd,
                                               const void* __restrict__ b1, const void* __restrict__ b2,
                                               const void* __restrict__ bd,
                                               const int* __restrict__ fmode,
                                               ushort_t* __restrict__ wt, ushort_t* __restrict__ w2lt,
                                               ushort_t* __restrict__ w2rt, ushort_t* __restrict__ wdt,
                                               float* __restrict__ b1f, float* __restrict__ b2f,
                                               float* __restrict__ bdf) {
    int idx = blockIdx.x * 256 + threadIdx.x;
    int bf = *fmode;
    if (idx < 65536) {
        int c = idx >> 8, k = idx & 255;
        float v = (k < 128) ? rdf(W1l, k * 256 + c, bf) : rdf(W1r, (k - 128) * 256 + c, bf);
        wt[c * 256 + k] = f2bf(v);
    } else if (idx < 81920) {
        int t = idx - 65536;
        int c = t >> 8, k = t & 255;
        w2lt[c * 256 + k] = f2bf(rdf(W2l, k * 64 + c, bf));
    } else if (idx < 98304) {
        int t = idx - 81920;
        int c = t >> 8, k = t & 255;
        w2rt[c * 256 + k] = f2bf(rdf(W2r, k * 64 + c, bf));
    } else if (idx < 106496) {
        int t = idx - 98304;
        int c = t >> 6, k = t & 63;
        wdt[c * 64 + k] = f2bf(rdf(Wd, k * 128 + c, bf));
    } else if (idx < 106752) {
        b1f[idx - 106496] = rdf(b1, idx - 106496, bf);
    } else if (idx < 106816) {
        b2f[idx - 106752] = rdf(b2, idx - 106752, bf);
    } else if (idx < 106944) {
        bdf[idx - 106816] = rdf(bd, idx - 106816, bf);
    }
}

// ---------------- agg1: meanx = mean of x rows (one wave/node, 4-way edge unroll) ----------------
__global__ __launch_bounds__(256) void k_agg128(const ushort_t* __restrict__ xb, const int* __restrict__ rowptr,
                                                const int* __restrict__ srclist, ushort_t* __restrict__ out) {
    int node = (blockIdx.x * 256 + threadIdx.x) >> 6;
    int lane = threadIdx.x & 63;
    if (node >= NN) return;
    int beg = rowptr[node], end = rowptr[node + 1];
    float a0 = 0.f, a1 = 0.f;
    int j = beg;
    for (; j + 3 < end; j += 4) {
        int s0 = srclist[j], s1 = srclist[j + 1], s2 = srclist[j + 2], s3 = srclist[j + 3];
        uint32_t p0 = *reinterpret_cast<const uint32_t*>(xb + (size_t)s0 * 128 + lane * 2);
        uint32_t p1 = *reinterpret_cast<const uint32_t*>(xb + (size_t)s1 * 128 + lane * 2);
        uint32_t p2 = *reinterpret_cast<const uint32_t*>(xb + (size_t)s2 * 128 + lane * 2);
        uint32_t p3 = *reinterpret_cast<const uint32_t*>(xb + (size_t)s3 * 128 + lane * 2);
        a0 += bf2f((uint16_t)(p0 & 0xffff)) + bf2f((uint16_t)(p1 & 0xffff))
            + bf2f((uint16_t)(p2 & 0xffff)) + bf2f((uint16_t)(p3 & 0xffff));
        a1 += bf2f((uint16_t)(p0 >> 16)) + bf2f((uint16_t)(p1 >> 16))
            + bf2f((uint16_t)(p2 >> 16)) + bf2f((uint16_t)(p3 >> 16));
    }
    for (; j < end; ++j) {
        int s = srclist[j];
        uint32_t p = *reinterpret_cast<const uint32_t*>(xb + (size_t)s * 128 + lane * 2);
        a0 += bf2f((uint16_t)(p & 0xffff));
        a1 += bf2f((uint16_t)(p >> 16));
    }
    float inv = 1.0f / (float)max(end - beg, 1);
    uint32_t o = (uint32_t)f2bf(a0 * inv) | ((uint32_t)f2bf(a1 * inv) << 16);
    *reinterpret_cast<uint32_t*>(out + (size_t)node * 128 + lane * 2) = o;
}

// ---------------- GEMM1 (MFMA): h = relu([meanx|xb] @ wt^T + b1), 16 rows/block ----------------
__global__ __launch_bounds__(256) void k_gemm1(const ushort_t* __restrict__ meanx, const ushort_t* __restrict__ xb,
                                               const ushort_t* __restrict__ wt, const float* __restrict__ b1f,
                                               ushort_t* __restrict__ h) {
    int wv = threadIdx.x >> 6, lane = threadIdx.x & 63;
    int m = lane & 15, q = lane >> 4;
    int r0 = blockIdx.x * 16;
    int row = r0 + m;
    f32x4 acc0 = {0.f, 0.f, 0.f, 0.f}, acc1 = acc0, acc2 = acc0, acc3 = acc0;
#pragma unroll
    for (int ks = 0; ks < 8; ++ks) {
        int kb = ks * 32 + q * 8;
        const ushort_t* ap = (kb < 128) ? (meanx + (size_t)row * 128 + kb)
                                        : (xb + (size_t)row * 128 + (kb - 128));
        bf16x8 a = *reinterpret_cast<const bf16x8*>(ap);
        const ushort_t* wb = wt + (size_t)(wv * 64 + m) * 256 + kb;
        bf16x8 b0 = *reinterpret_cast<const bf16x8*>(wb);
        bf16x8 b1v = *reinterpret_cast<const bf16x8*>(wb + 16 * 256);
        bf16x8 b2v = *reinterpret_cast<const bf16x8*>(wb + 32 * 256);
        bf16x8 b3v = *reinterpret_cast<const bf16x8*>(wb + 48 * 256);
        acc0 = __builtin_amdgcn_mfma_f32_16x16x32_bf16(a, b0, acc0, 0, 0, 0);
        acc1 = __builtin_amdgcn_mfma_f32_16x16x32_bf16(a, b1v, acc1, 0, 0, 0);
        acc2 = __builtin_amdgcn_mfma_f32_16x16x32_bf16(a, b2v, acc2, 0, 0, 0);
        acc3 = __builtin_amdgcn_mfma_f32_16x16x32_bf16(a, b3v, acc3, 0, 0, 0);
    }
    f32x4 accs[4] = {acc0, acc1, acc2, acc3};
#pragma unroll
    for (int ct = 0; ct < 4; ++ct) {
        int c = wv * 64 + ct * 16 + m;
        float bias = b1f[c];
#pragma unroll
        for (int i = 0; i < 4; ++i) {
            int rr = r0 + q * 4 + i;
            h[(size_t)rr * 256 + c] = f2bf(fmaxf(accs[ct][i] + bias, 0.f));
        }
    }
}

// ---------------- GEMM2a (MFMA): y = h@W2l (bf16), r = h@W2r + b2 (f32), 16 rows/block ----------------
__global__ __launch_bounds__(256) void k_gemm2a(const ushort_t* __restrict__ h,
                                                const ushort_t* __restrict__ w2lt, const ushort_t* __restrict__ w2rt,
                                                const float* __restrict__ b2f,
                                                ushort_t* __restrict__ y, float* __restrict__ r) {
    int wv = threadIdx.x >> 6, lane = threadIdx.x & 63;
    int m = lane & 15, q = lane >> 4;
    int r0 = blockIdx.x * 16;
    int row = r0 + m;
    int op = wv >> 1;
    int cb = (wv & 1) * 32;
    const ushort_t* wtx = op ? w2rt : w2lt;
    f32x4 acc0 = {0.f, 0.f, 0.f, 0.f}, acc1 = acc0;
#pragma unroll
    for (int ks = 0; ks < 8; ++ks) {
        int kb = ks * 32 + q * 8;
        bf16x8 a = *reinterpret_cast<const bf16x8*>(h + (size_t)row * 256 + kb);
        const ushort_t* wb = wtx + (size_t)(cb + m) * 256 + kb;
        bf16x8 b0 = *reinterpret_cast<const bf16x8*>(wb);
        bf16x8 b1v = *reinterpret_cast<const bf16x8*>(wb + 16 * 256);
        acc0 = __builtin_amdgcn_mfma_f32_16x16x32_bf16(a, b0, acc0, 0, 0, 0);
        acc1 = __builtin_amdgcn_mfma_f32_16x16x32_bf16(a, b1v, acc1, 0, 0, 0);
    }
    f32x4 accs[2] = {acc0, acc1};
#pragma unroll
    for (int ct = 0; ct < 2; ++ct) {
        int c = cb + ct * 16 + m;
#pragma unroll
        for (int i = 0; i < 4; ++i) {
            int rr = r0 + q * 4 + i;
            if (op == 0) {
                y[(size_t)rr * 64 + c] = f2bf(accs[ct][i]);
            } else {
                r[(size_t)rr * 64 + c] = accs[ct][i] + b2f[c];
            }
        }
    }
}

// ---------------- agg2y: z = mean(y over neighbors) + r ; write z f32 (out) + bf16 (zb) ----------------
__global__ __launch_bounds__(256) void k_agg2y(const ushort_t* __restrict__ y, const int* __restrict__ rowptr,
                                               const int* __restrict__ srclist, const float* __restrict__ r,
                                               float* __restrict__ zf, ushort_t* __restrict__ zb) {
    int node = (blockIdx.x * 256 + threadIdx.x) >> 6;
    int lane = threadIdx.x & 63;
    if (node >= NN) return;
    int half = lane >> 5, l32 = lane & 31;
    int beg = rowptr[node], end = rowptr[node + 1];
    float a0 = 0.f, a1 = 0.f;
    int j = beg + half;
    for (; j + 2 < end; j += 4) {
        int s0 = srclist[j], s1 = srclist[j + 2];
        uint32_t p0 = *reinterpret_cast<const uint32_t*>(y + (size_t)s0 * 64 + l32 * 2);
        uint32_t p1 = *reinterpret_cast<const uint32_t*>(y + (size_t)s1 * 64 + l32 * 2);
        a0 += bf2f((uint16_t)(p0 & 0xffff)) + bf2f((uint16_t)(p1 & 0xffff));
        a1 += bf2f((uint16_t)(p0 >> 16)) + bf2f((uint16_t)(p1 >> 16));
    }
    for (; j < end; j += 2) {
        int s = srclist[j];
        uint32_t p = *reinterpret_cast<const uint32_t*>(y + (size_t)s * 64 + l32 * 2);
        a0 += bf2f((uint16_t)(p & 0xffff));
        a1 += bf2f((uint16_t)(p >> 16));
    }
    a0 += __shfl_xor(a0, 32);
    a1 += __shfl_xor(a1, 32);
    if (half == 0) {
        float inv = 1.0f / (float)max(end - beg, 1);
        float2 rv = *reinterpret_cast<const float2*>(r + (size_t)node * 64 + l32 * 2);
        float z0 = a0 * inv + rv.x;
        float z1 = a1 * inv + rv.y;
        float2 zo; zo.x = z0; zo.y = z1;
        *reinterpret_cast<float2*>(zf + (size_t)node * 64 + l32 * 2) = zo;
        uint32_t o = (uint32_t)f2bf(z0) | ((uint32_t)f2bf(z1) << 16);
        *reinterpret_cast<uint32_t*>(zb + (size_t)node * 64 + l32 * 2) = o;
    }
}

// ---------------- GEMM3 (MFMA): x_hat = zb @ wdt^T + bd -> f32, 16 rows/block ----------------
__global__ __launch_bounds__(256) void k_gemm3(const ushort_t* __restrict__ zb, const ushort_t* __restrict__ wdt,
                                               const float* __restrict__ bdf, float* __restrict__ xhat) {
    int wv = threadIdx.x >> 6, lane = threadIdx.x & 63;
    int m = lane & 15, q = lane >> 4;
    int r0 = blockIdx.x * 16;
    int row = r0 + m;
    f32x4 acc0 = {0.f, 0.f, 0.f, 0.f}, acc1 = acc0;
#pragma unroll
    for (int ks = 0; ks < 2; ++ks) {
        int kb = ks * 32 + q * 8;
        bf16x8 a = *reinterpret_cast<const bf16x8*>(zb + (size_t)row * 64 + kb);
        const ushort_t* wb = wdt + (size_t)(wv * 32 + m) * 64 + kb;
        bf16x8 b0 = *reinterpret_cast<const bf16x8*>(wb);
        bf16x8 b1v = *reinterpret_cast<const bf16x8*>(wb + 16 * 64);
        acc0 = __builtin_amdgcn_mfma_f32_16x16x32_bf16(a, b0, acc0, 0, 0, 0);
        acc1 = __builtin_amdgcn_mfma_f32_16x16x32_bf16(a, b1v, acc1, 0, 0, 0);
    }
    f32x4 accs[2] = {acc0, acc1};
#pragma unroll
    for (int ct = 0; ct < 2; ++ct) {
        int c = wv * 32 + ct * 16 + m;
        float bias = bdf[c];
#pragma unroll
        for (int i = 0; i < 4; ++i) {
            int rr = r0 + q * 4 + i;
            xhat[(size_t)rr * 128 + c] = accs[ct][i] + bias;
        }
    }
}

extern "C" void kernel_launch(void* const* d_in, const int* in_sizes, int n_in,
                              void* d_out, int out_size, void* d_ws, size_t ws_size,
                              hipStream_t stream) {
    // ---- order-agnostic input identification by element count ----
    const void *px = nullptr, *pei = nullptr, *pW1l = nullptr, *pW1r = nullptr,
               *pW2l = nullptr, *pW2r = nullptr, *pWd = nullptr,
               *pb1 = nullptr, *pb2 = nullptr, *pbd = nullptr;
    for (int i = 0; i < n_in; ++i) {
        const void* p = d_in[i];
        switch (in_sizes[i]) {
            case 6400000: px  = p; break;
            case 1600000: pei = p; break;
            case 32768:   if (!pW1l) pW1l = p; else pW1r = p; break;
            case 16384:   if (!pW2l) pW2l = p; else pW2r = p; break;
            case 8192:    pWd = p; break;
            case 256:     pb1 = p; break;
            case 128:     pbd = p; break;
            case 64:      pb2 = p; break;
            default: break;
        }
    }
    if (!px || !pei || !pW1l || !pW1r || !pW2l || !pW2r || !pWd || !pb1 || !pb2 || !pbd) {
        px = d_in[0]; pei = d_in[1]; pW1l = d_in[2]; pb1 = d_in[3]; pW1r = d_in[4];
        pW2l = d_in[5]; pb2 = d_in[6]; pW2r = d_in[7]; pWd = d_in[8]; pbd = d_in[9];
    }
    const int* ei = (const int*)pei;

    // ---- workspace (~42.5 MB) ----
    char* base = (char*)d_ws;
    size_t off = 0;
    auto alloc = [&](size_t bytes) -> void* {
        void* r = base + off;
        off = (off + bytes + 255) & ~(size_t)255;
        return r;
    };
    int* mode     = (int*)alloc(4);
    int* fmode    = (int*)alloc(4);
    int* cnt      = (int*)alloc((size_t)NN * 4);
    int* rowptr   = (int*)alloc((size_t)(NN + 1) * 4);
    int* cursor   = (int*)alloc((size_t)NN * 4);
    int* blocksum = (int*)alloc((size_t)NB * 4);
    int* blockoff = (int*)alloc((size_t)NB * 4);
    int* srclist  = (int*)alloc((size_t)NE * 4);
    ushort_t* wt   = (ushort_t*)alloc((size_t)65536 * 2);
    ushort_t* w2lt = (ushort_t*)alloc((size_t)16384 * 2);
    ushort_t* w2rt = (ushort_t*)alloc((size_t)16384 * 2);
    ushort_t* wdt  = (ushort_t*)alloc((size_t)8192 * 2);
    float* b1f    = (float*)alloc(256 * 4);
    float* b2f    = (float*)alloc(64 * 4);
    float* bdf    = (float*)alloc(128 * 4);
    ushort_t* xb  = (ushort_t*)alloc((size_t)NN * 128 * 2);   // dead after gemm1
    ushort_t* h   = (ushort_t*)alloc((size_t)NN * 256 * 2);

    // outputs f32: z [NN,64] then x_hat [NN,128]
    float* out_z    = (float*)d_out;
    float* out_xhat = out_z + (size_t)NN * 64;

    // aliases:
    ushort_t* meanx = (ushort_t*)out_xhat;                       // [NN,128] bf16, dead after gemm1
    float*    rbuf  = (float*)((char*)out_xhat + (size_t)NN * 128 * 2); // [NN,64] f32, dead before gemm3
    ushort_t* y     = xb;                                        // [NN,64] bf16 (xb dead after gemm1)
    ushort_t* zb    = xb + (size_t)NN * 64;                      // [NN,64] bf16

    hipMemsetAsync(cnt, 0, (size_t)NN * 4, stream);

    k_detect<<<1, 256, 0, stream>>>(ei, mode);
    k_dtypef<<<1, 256, 0, stream>>>((const ushort_t*)px, fmode);

    int eb = (NE + 255) / 256;
    k_degree<<<eb, 256, 0, stream>>>(ei, mode, cnt);
    k_scanA<<<NB, 256, 0, stream>>>(cnt, rowptr, blocksum);
    k_scanB<<<1, 256, 0, stream>>>(blocksum, blockoff, rowptr);
    k_scanC<<<NB, 256, 0, stream>>>(rowptr, blockoff, cursor);
    k_fill<<<eb, 256, 0, stream>>>(ei, mode, cursor, srclist);

    k_cvt<<<(NN * 128 / 4 + 255) / 256, 256, 0, stream>>>(px, fmode, xb);
    k_prep3<<<418, 256, 0, stream>>>(pW1l, pW1r, pW2l, pW2r, pWd, pb1, pb2, pbd, fmode,
                                     wt, w2lt, w2rt, wdt, b1f, b2f, bdf);

    int ab = (NN + 3) / 4;                     // 12500 blocks, 4 waves each
    k_agg128<<<ab, 256, 0, stream>>>(xb, rowptr, srclist, meanx);

    int gb = NN / 16;                          // 3125
    k_gemm1<<<gb, 256, 0, stream>>>(meanx, xb, wt, b1f, h);
    k_gemm2a<<<gb, 256, 0, stream>>>(h, w2lt, w2rt, b2f, y, rbuf);
    k_agg2y<<<ab, 256, 0, stream>>>(y, rowptr, srclist, rbuf, out_z, zb);
    k_gemm3<<<gb, 256, 0, stream>>>(zb, wdt, bdf, out_xhat);
}

// Round 10
// 326.642 us; speedup vs baseline: 2.3560x; 1.1736x over previous
//
#include <hip/hip_runtime.h>
#include <stdint.h>

#define NN 50000
#define NE 800000
#define NB 196   // (NN+255)/256
// IN=128, HID=256, LAT=64

typedef __bf16 bf16x8 __attribute__((ext_vector_type(8)));
typedef float f32x4 __attribute__((ext_vector_type(4)));
typedef unsigned short ushort_t;

__device__ inline float bf2f(uint16_t u) {
    union { uint32_t i; float f; } v; v.i = ((uint32_t)u) << 16; return v.f;
}
__device__ inline uint16_t f2bf(float f) {
    uint32_t u = __float_as_uint(f);
    u += 0x7fffu + ((u >> 16) & 1u);
    return (uint16_t)(u >> 16);
}
__device__ inline float rdf(const void* p, int i, int bf) {
    return bf ? bf2f(((const ushort_t*)p)[i]) : ((const float*)p)[i];
}

// ---------------- edge dtype detection ----------------
__global__ __launch_bounds__(256) void k_detect(const int* __restrict__ ei, int* __restrict__ mode) {
    __shared__ int nz;
    if (threadIdx.x == 0) nz = 0;
    __syncthreads();
    int t = threadIdx.x;
    int v = ei[2 * t + 1] | ei[2 * (t + 256) + 1] | ei[2 * (t + 512) + 1] | ei[2 * (t + 768) + 1];
    if (v) atomicOr(&nz, 1);
    __syncthreads();
    if (t == 0) *mode = (nz == 0) ? 1 : 0;
}

// ---------------- float dtype detection ----------------
__global__ __launch_bounds__(256) void k_dtypef(const ushort_t* __restrict__ xw, int* __restrict__ fmode) {
    __shared__ int bad;
    if (threadIdx.x == 0) bad = 0;
    __syncthreads();
    int t = threadIdx.x;
#pragma unroll
    for (int r = 0; r < 2; ++r) {
        uint16_t w = xw[t + 256 * r];
        int e = (w >> 7) & 0xFF;
        if (!(w == 0 || (e >= 96 && e <= 144))) atomicOr(&bad, 1);
    }
    __syncthreads();
    if (t == 0) *fmode = (bad == 0) ? 1 : 0;
}

// ---------------- CSR build ----------------
__global__ __launch_bounds__(256) void k_degree(const int* __restrict__ ei, const int* __restrict__ mode,
                                                int* __restrict__ cnt) {
    int e = blockIdx.x * 256 + threadIdx.x;
    int sh = *mode;
    if (e < NE) {
        int d = ei[(size_t)(NE + e) << sh];
        atomicAdd(&cnt[d], 1);
    }
}

__device__ inline int block_scan256(int v, int* ws, int* btot) {
    int lane = threadIdx.x & 63, wv = threadIdx.x >> 6;
    int incl = v;
#pragma unroll
    for (int d = 1; d < 64; d <<= 1) {
        int n = __shfl_up(incl, d);
        if (lane >= d) incl += n;
    }
    if (lane == 63) ws[wv] = incl;
    __syncthreads();
    if (threadIdx.x == 0) {
        int r = 0;
#pragma unroll
        for (int k = 0; k < 4; ++k) { int t = ws[k]; ws[k] = r; r += t; }
        *btot = r;
    }
    __syncthreads();
    return ws[wv] + incl - v;
}

__global__ __launch_bounds__(256) void k_scanA(const int* __restrict__ cnt, int* __restrict__ rowptr,
                                               int* __restrict__ blocksum) {
    __shared__ int ws[4];
    __shared__ int btot;
    int i = blockIdx.x * 256 + threadIdx.x;
    int v = (i < NN) ? cnt[i] : 0;
    int excl = block_scan256(v, ws, &btot);
    if (i < NN) rowptr[i] = excl;
    if (threadIdx.x == 0) blocksum[blockIdx.x] = btot;
}

__global__ __launch_bounds__(256) void k_scanB(const int* __restrict__ blocksum, int* __restrict__ blockoff,
                                               int* __restrict__ rowptr) {
    __shared__ int ws[4];
    __shared__ int btot;
    int t = threadIdx.x;
    int v = (t < NB) ? blocksum[t] : 0;
    int excl = block_scan256(v, ws, &btot);
    if (t < NB) blockoff[t] = excl;
    if (t == NB - 1) rowptr[NN] = excl + v;
}

__global__ __launch_bounds__(256) void k_scanC(int* __restrict__ rowptr, const int* __restrict__ blockoff,
                                               int* __restrict__ cursor) {
    int i = blockIdx.x * 256 + threadIdx.x;
    if (i < NN) {
        int v = rowptr[i] + blockoff[blockIdx.x];
        rowptr[i] = v;
        cursor[i] = v;
    }
}

__global__ __launch_bounds__(256) void k_fill(const int* __restrict__ ei, const int* __restrict__ mode,
                                              int* __restrict__ cursor, int* __restrict__ srclist) {
    int e = blockIdx.x * 256 + threadIdx.x;
    int sh = *mode;
    if (e < NE) {
        int s = ei[(size_t)e << sh];
        int d = ei[(size_t)(NE + e) << sh];
        int p = atomicAdd(&cursor[d], 1);
        srclist[p] = s;
    }
}

// ---------------- x -> bf16 workspace copy ----------------
__global__ __launch_bounds__(256) void k_cvt(const void* __restrict__ x, const int* __restrict__ fmode,
                                             ushort_t* __restrict__ xb) {
    int i = blockIdx.x * 256 + threadIdx.x;
    const int total = NN * 128 / 4;
    if (i >= total) return;
    if (*fmode) {
        reinterpret_cast<ushort4*>(xb)[i] = reinterpret_cast<const ushort4*>(x)[i];
    } else {
        float4 v = reinterpret_cast<const float4*>(x)[i];
        ushort4 o;
        o.x = f2bf(v.x); o.y = f2bf(v.y); o.z = f2bf(v.z); o.w = f2bf(v.w);
        reinterpret_cast<ushort4*>(xb)[i] = o;
    }
}

// ---------------- weight prep: transposed bf16 for MFMA B-operand ----------------
__global__ __launch_bounds__(256) void k_prep3(const void* __restrict__ W1l, const void* __restrict__ W1r,
                                               const void* __restrict__ W2l, const void* __restrict__ W2r,
                                               const void* __restrict__ Wd,
                                               const void* __restrict__ b1, const void* __restrict__ b2,
                                               const void* __restrict__ bd,
                                               const int* __restrict__ fmode,
                                               ushort_t* __restrict__ wt, ushort_t* __restrict__ w2lt,
                                               ushort_t* __restrict__ w2rt, ushort_t* __restrict__ wdt,
                                               float* __restrict__ b1f, float* __restrict__ b2f,
                                               float* __restrict__ bdf) {
    int idx = blockIdx.x * 256 + threadIdx.x;
    int bf = *fmode;
    if (idx < 65536) {
        int c = idx >> 8, k = idx & 255;
        float v = (k < 128) ? rdf(W1l, k * 256 + c, bf) : rdf(W1r, (k - 128) * 256 + c, bf);
        wt[c * 256 + k] = f2bf(v);
    } else if (idx < 81920) {
        int t = idx - 65536;
        int c = t >> 8, k = t & 255;
        w2lt[c * 256 + k] = f2bf(rdf(W2l, k * 64 + c, bf));
    } else if (idx < 98304) {
        int t = idx - 81920;
        int c = t >> 8, k = t & 255;
        w2rt[c * 256 + k] = f2bf(rdf(W2r, k * 64 + c, bf));
    } else if (idx < 106496) {
        int t = idx - 98304;
        int c = t >> 6, k = t & 63;
        wdt[c * 64 + k] = f2bf(rdf(Wd, k * 128 + c, bf));
    } else if (idx < 106752) {
        b1f[idx - 106496] = rdf(b1, idx - 106496, bf);
    } else if (idx < 106816) {
        b2f[idx - 106752] = rdf(b2, idx - 106752, bf);
    } else if (idx < 106944) {
        bdf[idx - 106816] = rdf(bd, idx - 106816, bf);
    }
}

// ---------------- agg1: meanx = mean of x rows (one wave/node, 4-way edge unroll) ----------------
__global__ __launch_bounds__(256) void k_agg128(const ushort_t* __restrict__ xb, const int* __restrict__ rowptr,
                                                const int* __restrict__ srclist, ushort_t* __restrict__ out) {
    int node = (blockIdx.x * 256 + threadIdx.x) >> 6;
    int lane = threadIdx.x & 63;
    if (node >= NN) return;
    int beg = rowptr[node], end = rowptr[node + 1];
    float a0 = 0.f, a1 = 0.f;
    int j = beg;
    for (; j + 3 < end; j += 4) {
        int s0 = srclist[j], s1 = srclist[j + 1], s2 = srclist[j + 2], s3 = srclist[j + 3];
        uint32_t p0 = *reinterpret_cast<const uint32_t*>(xb + (size_t)s0 * 128 + lane * 2);
        uint32_t p1 = *reinterpret_cast<const uint32_t*>(xb + (size_t)s1 * 128 + lane * 2);
        uint32_t p2 = *reinterpret_cast<const uint32_t*>(xb + (size_t)s2 * 128 + lane * 2);
        uint32_t p3 = *reinterpret_cast<const uint32_t*>(xb + (size_t)s3 * 128 + lane * 2);
        a0 += bf2f((uint16_t)(p0 & 0xffff)) + bf2f((uint16_t)(p1 & 0xffff))
            + bf2f((uint16_t)(p2 & 0xffff)) + bf2f((uint16_t)(p3 & 0xffff));
        a1 += bf2f((uint16_t)(p0 >> 16)) + bf2f((uint16_t)(p1 >> 16))
            + bf2f((uint16_t)(p2 >> 16)) + bf2f((uint16_t)(p3 >> 16));
    }
    for (; j < end; ++j) {
        int s = srclist[j];
        uint32_t p = *reinterpret_cast<const uint32_t*>(xb + (size_t)s * 128 + lane * 2);
        a0 += bf2f((uint16_t)(p & 0xffff));
        a1 += bf2f((uint16_t)(p >> 16));
    }
    float inv = 1.0f / (float)max(end - beg, 1);
    uint32_t o = (uint32_t)f2bf(a0 * inv) | ((uint32_t)f2bf(a1 * inv) << 16);
    *reinterpret_cast<uint32_t*>(out + (size_t)node * 128 + lane * 2) = o;
}

// ---------------- GEMM1 (persistent-B MFMA): h = relu([meanx|xb] @ wt^T + b1) ----------------
// B-fragments (64 cols/wave x K=256) hoisted into 128 VGPRs; grid-stride over 16-row tiles.
__global__ __launch_bounds__(256, 2) void k_gemm1p(const ushort_t* __restrict__ meanx, const ushort_t* __restrict__ xb,
                                                   const ushort_t* __restrict__ wt, const float* __restrict__ b1f,
                                                   ushort_t* __restrict__ h) {
    int wv = threadIdx.x >> 6, lane = threadIdx.x & 63;
    int m = lane & 15, q = lane >> 4;
    bf16x8 B[8][4];
#pragma unroll
    for (int ks = 0; ks < 8; ++ks) {
        int kb = ks * 32 + q * 8;
#pragma unroll
        for (int ct = 0; ct < 4; ++ct)
            B[ks][ct] = *reinterpret_cast<const bf16x8*>(wt + (size_t)(wv * 64 + ct * 16 + m) * 256 + kb);
    }
    const int ntiles = NN / 16;   // 3125
    for (int t = blockIdx.x; t < ntiles; t += gridDim.x) {
        int r0 = t * 16;
        int row = r0 + m;
        f32x4 acc[4];
#pragma unroll
        for (int ct = 0; ct < 4; ++ct) acc[ct] = (f32x4){0.f, 0.f, 0.f, 0.f};
#pragma unroll
        for (int ks = 0; ks < 8; ++ks) {
            int kb = ks * 32 + q * 8;
            const ushort_t* ap = (ks < 4) ? (meanx + (size_t)row * 128 + kb)
                                          : (xb + (size_t)row * 128 + (kb - 128));
            bf16x8 a = *reinterpret_cast<const bf16x8*>(ap);
#pragma unroll
            for (int ct = 0; ct < 4; ++ct)
                acc[ct] = __builtin_amdgcn_mfma_f32_16x16x32_bf16(a, B[ks][ct], acc[ct], 0, 0, 0);
        }
#pragma unroll
        for (int ct = 0; ct < 4; ++ct) {
            int c = wv * 64 + ct * 16 + m;
            float bias = b1f[c];
#pragma unroll
            for (int i = 0; i < 4; ++i) {
                int rr = r0 + q * 4 + i;
                h[(size_t)rr * 256 + c] = f2bf(fmaxf(acc[ct][i] + bias, 0.f));
            }
        }
    }
}

// ---------------- GEMM2 (persistent-B): y = h@W2l (bf16), r = h@W2r + b2 (f32) ----------------
__global__ __launch_bounds__(256, 2) void k_gemm2p(const ushort_t* __restrict__ h,
                                                   const ushort_t* __restrict__ w2lt, const ushort_t* __restrict__ w2rt,
                                                   const float* __restrict__ b2f,
                                                   ushort_t* __restrict__ y, float* __restrict__ r) {
    int wv = threadIdx.x >> 6, lane = threadIdx.x & 63;
    int m = lane & 15, q = lane >> 4;
    int op = wv >> 1;                  // 0 = y (W2l), 1 = r (W2r)
    int cb = (wv & 1) * 32;
    const ushort_t* wtx = op ? w2rt : w2lt;
    bf16x8 B[8][2];
#pragma unroll
    for (int ks = 0; ks < 8; ++ks) {
        int kb = ks * 32 + q * 8;
#pragma unroll
        for (int ct = 0; ct < 2; ++ct)
            B[ks][ct] = *reinterpret_cast<const bf16x8*>(wtx + (size_t)(cb + ct * 16 + m) * 256 + kb);
    }
    const int ntiles = NN / 16;
    for (int t = blockIdx.x; t < ntiles; t += gridDim.x) {
        int r0 = t * 16;
        int row = r0 + m;
        f32x4 acc[2];
        acc[0] = (f32x4){0.f, 0.f, 0.f, 0.f}; acc[1] = acc[0];
#pragma unroll
        for (int ks = 0; ks < 8; ++ks) {
            int kb = ks * 32 + q * 8;
            bf16x8 a = *reinterpret_cast<const bf16x8*>(h + (size_t)row * 256 + kb);
#pragma unroll
            for (int ct = 0; ct < 2; ++ct)
                acc[ct] = __builtin_amdgcn_mfma_f32_16x16x32_bf16(a, B[ks][ct], acc[ct], 0, 0, 0);
        }
#pragma unroll
        for (int ct = 0; ct < 2; ++ct) {
            int c = cb + ct * 16 + m;
#pragma unroll
            for (int i = 0; i < 4; ++i) {
                int rr = r0 + q * 4 + i;
                if (op == 0) y[(size_t)rr * 64 + c] = f2bf(acc[ct][i]);
                else         r[(size_t)rr * 64 + c] = acc[ct][i] + b2f[c];
            }
        }
    }
}

// ---------------- agg2y: z = mean(y over neighbors) + r ; z f32 (out) + bf16 (zb) ----------------
__global__ __launch_bounds__(256) void k_agg2y(const ushort_t* __restrict__ y, const int* __restrict__ rowptr,
                                               const int* __restrict__ srclist, const float* __restrict__ r,
                                               float* __restrict__ zf, ushort_t* __restrict__ zb) {
    int node = (blockIdx.x * 256 + threadIdx.x) >> 6;
    int lane = threadIdx.x & 63;
    if (node >= NN) return;
    int half = lane >> 5, l32 = lane & 31;
    int beg = rowptr[node], end = rowptr[node + 1];
    float a0 = 0.f, a1 = 0.f;
    int j = beg + half;
    for (; j + 2 < end; j += 4) {
        int s0 = srclist[j], s1 = srclist[j + 2];
        uint32_t p0 = *reinterpret_cast<const uint32_t*>(y + (size_t)s0 * 64 + l32 * 2);
        uint32_t p1 = *reinterpret_cast<const uint32_t*>(y + (size_t)s1 * 64 + l32 * 2);
        a0 += bf2f((uint16_t)(p0 & 0xffff)) + bf2f((uint16_t)(p1 & 0xffff));
        a1 += bf2f((uint16_t)(p0 >> 16)) + bf2f((uint16_t)(p1 >> 16));
    }
    for (; j < end; j += 2) {
        int s = srclist[j];
        uint32_t p = *reinterpret_cast<const uint32_t*>(y + (size_t)s * 64 + l32 * 2);
        a0 += bf2f((uint16_t)(p & 0xffff));
        a1 += bf2f((uint16_t)(p >> 16));
    }
    a0 += __shfl_xor(a0, 32);
    a1 += __shfl_xor(a1, 32);
    if (half == 0) {
        float inv = 1.0f / (float)max(end - beg, 1);
        float2 rv = *reinterpret_cast<const float2*>(r + (size_t)node * 64 + l32 * 2);
        float z0 = a0 * inv + rv.x;
        float z1 = a1 * inv + rv.y;
        float2 zo; zo.x = z0; zo.y = z1;
        *reinterpret_cast<float2*>(zf + (size_t)node * 64 + l32 * 2) = zo;
        uint32_t o = (uint32_t)f2bf(z0) | ((uint32_t)f2bf(z1) << 16);
        *reinterpret_cast<uint32_t*>(zb + (size_t)node * 64 + l32 * 2) = o;
    }
}

// ---------------- GEMM3 (persistent-B): x_hat = zb @ wdt^T + bd -> f32 ----------------
__global__ __launch_bounds__(256, 2) void k_gemm3p(const ushort_t* __restrict__ zb, const ushort_t* __restrict__ wdt,
                                                   const float* __restrict__ bdf, float* __restrict__ xhat) {
    int wv = threadIdx.x >> 6, lane = threadIdx.x & 63;
    int m = lane & 15, q = lane >> 4;
    bf16x8 B[2][2];
#pragma unroll
    for (int ks = 0; ks < 2; ++ks) {
        int kb = ks * 32 + q * 8;
#pragma unroll
        for (int ct = 0; ct < 2; ++ct)
            B[ks][ct] = *reinterpret_cast<const bf16x8*>(wdt + (size_t)(wv * 32 + ct * 16 + m) * 64 + kb);
    }
    const int ntiles = NN / 16;
    for (int t = blockIdx.x; t < ntiles; t += gridDim.x) {
        int r0 = t * 16;
        int row = r0 + m;
        f32x4 acc[2];
        acc[0] = (f32x4){0.f, 0.f, 0.f, 0.f}; acc[1] = acc[0];
#pragma unroll
        for (int ks = 0; ks < 2; ++ks) {
            int kb = ks * 32 + q * 8;
            bf16x8 a = *reinterpret_cast<const bf16x8*>(zb + (size_t)row * 64 + kb);
#pragma unroll
            for (int ct = 0; ct < 2; ++ct)
                acc[ct] = __builtin_amdgcn_mfma_f32_16x16x32_bf16(a, B[ks][ct], acc[ct], 0, 0, 0);
        }
#pragma unroll
        for (int ct = 0; ct < 2; ++ct) {
            int c = wv * 32 + ct * 16 + m;
            float bias = bdf[c];
#pragma unroll
            for (int i = 0; i < 4; ++i) {
                int rr = r0 + q * 4 + i;
                xhat[(size_t)rr * 128 + c] = acc[ct][i] + bias;
            }
        }
    }
}

extern "C" void kernel_launch(void* const* d_in, const int* in_sizes, int n_in,
                              void* d_out, int out_size, void* d_ws, size_t ws_size,
                              hipStream_t stream) {
    // ---- order-agnostic input identification by element count ----
    const void *px = nullptr, *pei = nullptr, *pW1l = nullptr, *pW1r = nullptr,
               *pW2l = nullptr, *pW2r = nullptr, *pWd = nullptr,
               *pb1 = nullptr, *pb2 = nullptr, *pbd = nullptr;
    for (int i = 0; i < n_in; ++i) {
        const void* p = d_in[i];
        switch (in_sizes[i]) {
            case 6400000: px  = p; break;
            case 1600000: pei = p; break;
            case 32768:   if (!pW1l) pW1l = p; else pW1r = p; break;
            case 16384:   if (!pW2l) pW2l = p; else pW2r = p; break;
            case 8192:    pWd = p; break;
            case 256:     pb1 = p; break;
            case 128:     pbd = p; break;
            case 64:      pb2 = p; break;
            default: break;
        }
    }
    if (!px || !pei || !pW1l || !pW1r || !pW2l || !pW2r || !pWd || !pb1 || !pb2 || !pbd) {
        px = d_in[0]; pei = d_in[1]; pW1l = d_in[2]; pb1 = d_in[3]; pW1r = d_in[4];
        pW2l = d_in[5]; pb2 = d_in[6]; pW2r = d_in[7]; pWd = d_in[8]; pbd = d_in[9];
    }
    const int* ei = (const int*)pei;

    // ---- workspace (~42.5 MB) ----
    char* base = (char*)d_ws;
    size_t off = 0;
    auto alloc = [&](size_t bytes) -> void* {
        void* r = base + off;
        off = (off + bytes + 255) & ~(size_t)255;
        return r;
    };
    int* mode     = (int*)alloc(4);
    int* fmode    = (int*)alloc(4);
    int* cnt      = (int*)alloc((size_t)NN * 4);
    int* rowptr   = (int*)alloc((size_t)(NN + 1) * 4);
    int* cursor   = (int*)alloc((size_t)NN * 4);
    int* blocksum = (int*)alloc((size_t)NB * 4);
    int* blockoff = (int*)alloc((size_t)NB * 4);
    int* srclist  = (int*)alloc((size_t)NE * 4);
    ushort_t* wt   = (ushort_t*)alloc((size_t)65536 * 2);
    ushort_t* w2lt = (ushort_t*)alloc((size_t)16384 * 2);
    ushort_t* w2rt = (ushort_t*)alloc((size_t)16384 * 2);
    ushort_t* wdt  = (ushort_t*)alloc((size_t)8192 * 2);
    float* b1f    = (float*)alloc(256 * 4);
    float* b2f    = (float*)alloc(64 * 4);
    float* bdf    = (float*)alloc(128 * 4);
    ushort_t* xb  = (ushort_t*)alloc((size_t)NN * 128 * 2);   // dead after gemm1
    ushort_t* h   = (ushort_t*)alloc((size_t)NN * 256 * 2);

    // outputs f32: z [NN,64] then x_hat [NN,128]
    float* out_z    = (float*)d_out;
    float* out_xhat = out_z + (size_t)NN * 64;

    // aliases:
    ushort_t* meanx = (ushort_t*)out_xhat;                       // [NN,128] bf16, dead after gemm1
    float*    rbuf  = (float*)((char*)out_xhat + (size_t)NN * 128 * 2); // [NN,64] f32, dead before gemm3
    ushort_t* y     = xb;                                        // [NN,64] bf16 (xb dead after gemm1)
    ushort_t* zb    = xb + (size_t)NN * 64;                      // [NN,64] bf16

    hipMemsetAsync(cnt, 0, (size_t)NN * 4, stream);

    k_detect<<<1, 256, 0, stream>>>(ei, mode);
    k_dtypef<<<1, 256, 0, stream>>>((const ushort_t*)px, fmode);

    int eb = (NE + 255) / 256;
    k_degree<<<eb, 256, 0, stream>>>(ei, mode, cnt);
    k_scanA<<<NB, 256, 0, stream>>>(cnt, rowptr, blocksum);
    k_scanB<<<1, 256, 0, stream>>>(blocksum, blockoff, rowptr);
    k_scanC<<<NB, 256, 0, stream>>>(rowptr, blockoff, cursor);
    k_fill<<<eb, 256, 0, stream>>>(ei, mode, cursor, srclist);

    k_cvt<<<(NN * 128 / 4 + 255) / 256, 256, 0, stream>>>(px, fmode, xb);
    k_prep3<<<418, 256, 0, stream>>>(pW1l, pW1r, pW2l, pW2r, pWd, pb1, pb2, pbd, fmode,
                                     wt, w2lt, w2rt, wdt, b1f, b2f, bdf);

    int ab = (NN + 3) / 4;                     // 12500 blocks, 4 waves each
    k_agg128<<<ab, 256, 0, stream>>>(xb, rowptr, srclist, meanx);

    k_gemm1p<<<512, 256, 0, stream>>>(meanx, xb, wt, b1f, h);
    k_gemm2p<<<512, 256, 0, stream>>>(h, w2lt, w2rt, b2f, y, rbuf);
    k_agg2y<<<ab, 256, 0, stream>>>(y, rowptr, srclist, rbuf, out_z, zb);
    k_gemm3p<<<512, 256, 0, stream>>>(zb, wdt, bdf, out_xhat);
}

// Round 11
// 315.665 us; speedup vs baseline: 2.4379x; 1.0348x over previous
//
#include <hip/hip_runtime.h>
#include <stdint.h>

#define NN 50000
#define NE 800000
#define NB 196   // (NN+255)/256
#define CS 32    // counter stride (ints) = one counter per 128B line
// IN=128, HID=256, LAT=64

typedef __bf16 bf16x8 __attribute__((ext_vector_type(8)));
typedef float f32x4 __attribute__((ext_vector_type(4)));
typedef unsigned short ushort_t;

__device__ inline float bf2f(uint16_t u) {
    union { uint32_t i; float f; } v; v.i = ((uint32_t)u) << 16; return v.f;
}
__device__ inline uint16_t f2bf(float f) {
    uint32_t u = __float_as_uint(f);
    u += 0x7fffu + ((u >> 16) & 1u);
    return (uint16_t)(u >> 16);
}
__device__ inline float rdf(const void* p, int i, int bf) {
    return bf ? bf2f(((const ushort_t*)p)[i]) : ((const float*)p)[i];
}

// ---------------- combined mode detection: edge dtype + float dtype ----------------
__global__ __launch_bounds__(256) void k_modes(const int* __restrict__ ei, const ushort_t* __restrict__ xw,
                                               int* __restrict__ mode, int* __restrict__ fmode) {
    __shared__ int nz, bad;
    if (threadIdx.x == 0) { nz = 0; bad = 0; }
    __syncthreads();
    int t = threadIdx.x;
    int v = ei[2 * t + 1] | ei[2 * (t + 256) + 1] | ei[2 * (t + 512) + 1] | ei[2 * (t + 768) + 1];
    if (v) atomicOr(&nz, 1);
#pragma unroll
    for (int r = 0; r < 2; ++r) {
        uint16_t w = xw[t + 256 * r];
        int e = (w >> 7) & 0xFF;
        if (!(w == 0 || (e >= 96 && e <= 144))) atomicOr(&bad, 1);
    }
    __syncthreads();
    if (t == 0) { *mode = (nz == 0) ? 1 : 0; *fmode = (bad == 0) ? 1 : 0; }
}

// ---------------- CSR build (padded counters: cnt/cursor stride CS) ----------------
__global__ __launch_bounds__(256) void k_degree(const int* __restrict__ ei, const int* __restrict__ mode,
                                                int* __restrict__ cnt) {
    int e = blockIdx.x * 256 + threadIdx.x;
    int sh = *mode;
    if (e < NE) {
        int d = ei[(size_t)(NE + e) << sh];
        atomicAdd(&cnt[d * CS], 1);
    }
}

__device__ inline int block_scan256(int v, int* ws, int* btot) {
    int lane = threadIdx.x & 63, wv = threadIdx.x >> 6;
    int incl = v;
#pragma unroll
    for (int d = 1; d < 64; d <<= 1) {
        int n = __shfl_up(incl, d);
        if (lane >= d) incl += n;
    }
    if (lane == 63) ws[wv] = incl;
    __syncthreads();
    if (threadIdx.x == 0) {
        int r = 0;
#pragma unroll
        for (int k = 0; k < 4; ++k) { int t = ws[k]; ws[k] = r; r += t; }
        *btot = r;
    }
    __syncthreads();
    return ws[wv] + incl - v;
}

__global__ __launch_bounds__(256) void k_scanA(const int* __restrict__ cnt, int* __restrict__ rowptr,
                                               int* __restrict__ blocksum) {
    __shared__ int ws[4];
    __shared__ int btot;
    int i = blockIdx.x * 256 + threadIdx.x;
    int v = (i < NN) ? cnt[(size_t)i * CS] : 0;
    int excl = block_scan256(v, ws, &btot);
    if (i < NN) rowptr[i] = excl;
    if (threadIdx.x == 0) blocksum[blockIdx.x] = btot;
}

__global__ __launch_bounds__(256) void k_scanB(const int* __restrict__ blocksum, int* __restrict__ blockoff,
                                               int* __restrict__ rowptr) {
    __shared__ int ws[4];
    __shared__ int btot;
    int t = threadIdx.x;
    int v = (t < NB) ? blocksum[t] : 0;
    int excl = block_scan256(v, ws, &btot);
    if (t < NB) blockoff[t] = excl;
    if (t == NB - 1) rowptr[NN] = excl + v;
}

__global__ __launch_bounds__(256) void k_scanC(int* __restrict__ rowptr, const int* __restrict__ blockoff,
                                               int* __restrict__ cursor) {
    int i = blockIdx.x * 256 + threadIdx.x;
    if (i < NN) {
        int v = rowptr[i] + blockoff[blockIdx.x];
        rowptr[i] = v;
        cursor[(size_t)i * CS] = v;
    }
}

__global__ __launch_bounds__(256) void k_fill(const int* __restrict__ ei, const int* __restrict__ mode,
                                              int* __restrict__ cursor, ushort_t* __restrict__ srclist) {
    int e = blockIdx.x * 256 + threadIdx.x;
    int sh = *mode;
    if (e < NE) {
        int s = ei[(size_t)e << sh];
        int d = ei[(size_t)(NE + e) << sh];
        int p = atomicAdd(&cursor[d * CS], 1);
        srclist[p] = (ushort_t)s;
    }
}

// ---------------- x -> bf16 workspace copy ----------------
__global__ __launch_bounds__(256) void k_cvt(const void* __restrict__ x, const int* __restrict__ fmode,
                                             ushort_t* __restrict__ xb) {
    int i = blockIdx.x * 256 + threadIdx.x;
    const int total = NN * 128 / 4;
    if (i >= total) return;
    if (*fmode) {
        reinterpret_cast<ushort4*>(xb)[i] = reinterpret_cast<const ushort4*>(x)[i];
    } else {
        float4 v = reinterpret_cast<const float4*>(x)[i];
        ushort4 o;
        o.x = f2bf(v.x); o.y = f2bf(v.y); o.z = f2bf(v.z); o.w = f2bf(v.w);
        reinterpret_cast<ushort4*>(xb)[i] = o;
    }
}

// ---------------- weight prep: transposed bf16 for MFMA B-operand ----------------
__global__ __launch_bounds__(256) void k_prep3(const void* __restrict__ W1l, const void* __restrict__ W1r,
                                               const void* __restrict__ W2l, const void* __restrict__ W2r,
                                               const void* __restrict__ Wd,
                                               const void* __restrict__ b1, const void* __restrict__ b2,
                                               const void* __restrict__ bd,
                                               const int* __restrict__ fmode,
                                               ushort_t* __restrict__ wt, ushort_t* __restrict__ w2lt,
                                               ushort_t* __restrict__ w2rt, ushort_t* __restrict__ wdt,
                                               float* __restrict__ b1f, float* __restrict__ b2f,
                                               float* __restrict__ bdf) {
    int idx = blockIdx.x * 256 + threadIdx.x;
    int bf = *fmode;
    if (idx < 65536) {
        int c = idx >> 8, k = idx & 255;
        float v = (k < 128) ? rdf(W1l, k * 256 + c, bf) : rdf(W1r, (k - 128) * 256 + c, bf);
        wt[c * 256 + k] = f2bf(v);
    } else if (idx < 81920) {
        int t = idx - 65536;
        int c = t >> 8, k = t & 255;
        w2lt[c * 256 + k] = f2bf(rdf(W2l, k * 64 + c, bf));
    } else if (idx < 98304) {
        int t = idx - 81920;
        int c = t >> 8, k = t & 255;
        w2rt[c * 256 + k] = f2bf(rdf(W2r, k * 64 + c, bf));
    } else if (idx < 106496) {
        int t = idx - 98304;
        int c = t >> 6, k = t & 63;
        wdt[c * 64 + k] = f2bf(rdf(Wd, k * 128 + c, bf));
    } else if (idx < 106752) {
        b1f[idx - 106496] = rdf(b1, idx - 106496, bf);
    } else if (idx < 106816) {
        b2f[idx - 106752] = rdf(b2, idx - 106752, bf);
    } else if (idx < 106944) {
        bdf[idx - 106816] = rdf(bd, idx - 106816, bf);
    }
}

// ---------------- agg1: meanx = mean of x rows (one wave/node, 4-way edge unroll) ----------------
__global__ __launch_bounds__(256) void k_agg128(const ushort_t* __restrict__ xb, const int* __restrict__ rowptr,
                                                const ushort_t* __restrict__ srclist, ushort_t* __restrict__ out) {
    int node = (blockIdx.x * 256 + threadIdx.x) >> 6;
    int lane = threadIdx.x & 63;
    if (node >= NN) return;
    int beg = rowptr[node], end = rowptr[node + 1];
    float a0 = 0.f, a1 = 0.f;
    int j = beg;
    for (; j + 3 < end; j += 4) {
        int s0 = srclist[j], s1 = srclist[j + 1], s2 = srclist[j + 2], s3 = srclist[j + 3];
        uint32_t p0 = *reinterpret_cast<const uint32_t*>(xb + (size_t)s0 * 128 + lane * 2);
        uint32_t p1 = *reinterpret_cast<const uint32_t*>(xb + (size_t)s1 * 128 + lane * 2);
        uint32_t p2 = *reinterpret_cast<const uint32_t*>(xb + (size_t)s2 * 128 + lane * 2);
        uint32_t p3 = *reinterpret_cast<const uint32_t*>(xb + (size_t)s3 * 128 + lane * 2);
        a0 += bf2f((uint16_t)(p0 & 0xffff)) + bf2f((uint16_t)(p1 & 0xffff))
            + bf2f((uint16_t)(p2 & 0xffff)) + bf2f((uint16_t)(p3 & 0xffff));
        a1 += bf2f((uint16_t)(p0 >> 16)) + bf2f((uint16_t)(p1 >> 16))
            + bf2f((uint16_t)(p2 >> 16)) + bf2f((uint16_t)(p3 >> 16));
    }
    for (; j < end; ++j) {
        int s = srclist[j];
        uint32_t p = *reinterpret_cast<const uint32_t*>(xb + (size_t)s * 128 + lane * 2);
        a0 += bf2f((uint16_t)(p & 0xffff));
        a1 += bf2f((uint16_t)(p >> 16));
    }
    float inv = 1.0f / (float)max(end - beg, 1);
    uint32_t o = (uint32_t)f2bf(a0 * inv) | ((uint32_t)f2bf(a1 * inv) << 16);
    *reinterpret_cast<uint32_t*>(out + (size_t)node * 128 + lane * 2) = o;
}

// ---------------- GEMM1 (persistent-B MFMA): h = relu([meanx|xb] @ wt^T + b1) ----------------
__global__ __launch_bounds__(256, 2) void k_gemm1p(const ushort_t* __restrict__ meanx, const ushort_t* __restrict__ xb,
                                                   const ushort_t* __restrict__ wt, const float* __restrict__ b1f,
                                                   ushort_t* __restrict__ h) {
    int wv = threadIdx.x >> 6, lane = threadIdx.x & 63;
    int m = lane & 15, q = lane >> 4;
    bf16x8 B[8][4];
#pragma unroll
    for (int ks = 0; ks < 8; ++ks) {
        int kb = ks * 32 + q * 8;
#pragma unroll
        for (int ct = 0; ct < 4; ++ct)
            B[ks][ct] = *reinterpret_cast<const bf16x8*>(wt + (size_t)(wv * 64 + ct * 16 + m) * 256 + kb);
    }
    const int ntiles = NN / 16;   // 3125
    for (int t = blockIdx.x; t < ntiles; t += gridDim.x) {
        int r0 = t * 16;
        int row = r0 + m;
        f32x4 acc[4];
#pragma unroll
        for (int ct = 0; ct < 4; ++ct) acc[ct] = (f32x4){0.f, 0.f, 0.f, 0.f};
#pragma unroll
        for (int ks = 0; ks < 8; ++ks) {
            int kb = ks * 32 + q * 8;
            const ushort_t* ap = (ks < 4) ? (meanx + (size_t)row * 128 + kb)
                                          : (xb + (size_t)row * 128 + (kb - 128));
            bf16x8 a = *reinterpret_cast<const bf16x8*>(ap);
#pragma unroll
            for (int ct = 0; ct < 4; ++ct)
                acc[ct] = __builtin_amdgcn_mfma_f32_16x16x32_bf16(a, B[ks][ct], acc[ct], 0, 0, 0);
        }
#pragma unroll
        for (int ct = 0; ct < 4; ++ct) {
            int c = wv * 64 + ct * 16 + m;
            float bias = b1f[c];
#pragma unroll
            for (int i = 0; i < 4; ++i) {
                int rr = r0 + q * 4 + i;
                h[(size_t)rr * 256 + c] = f2bf(fmaxf(acc[ct][i] + bias, 0.f));
            }
        }
    }
}

// ---------------- GEMM2 (persistent-B): y = h@W2l (bf16), r = h@W2r + b2 (f32) ----------------
__global__ __launch_bounds__(256, 2) void k_gemm2p(const ushort_t* __restrict__ h,
                                                   const ushort_t* __restrict__ w2lt, const ushort_t* __restrict__ w2rt,
                                                   const float* __restrict__ b2f,
                                                   ushort_t* __restrict__ y, float* __restrict__ r) {
    int wv = threadIdx.x >> 6, lane = threadIdx.x & 63;
    int m = lane & 15, q = lane >> 4;
    int op = wv >> 1;
    int cb = (wv & 1) * 32;
    const ushort_t* wtx = op ? w2rt : w2lt;
    bf16x8 B[8][2];
#pragma unroll
    for (int ks = 0; ks < 8; ++ks) {
        int kb = ks * 32 + q * 8;
#pragma unroll
        for (int ct = 0; ct < 2; ++ct)
            B[ks][ct] = *reinterpret_cast<const bf16x8*>(wtx + (size_t)(cb + ct * 16 + m) * 256 + kb);
    }
    const int ntiles = NN / 16;
    for (int t = blockIdx.x; t < ntiles; t += gridDim.x) {
        int r0 = t * 16;
        int row = r0 + m;
        f32x4 acc[2];
        acc[0] = (f32x4){0.f, 0.f, 0.f, 0.f}; acc[1] = acc[0];
#pragma unroll
        for (int ks = 0; ks < 8; ++ks) {
            int kb = ks * 32 + q * 8;
            bf16x8 a = *reinterpret_cast<const bf16x8*>(h + (size_t)row * 256 + kb);
#pragma unroll
            for (int ct = 0; ct < 2; ++ct)
                acc[ct] = __builtin_amdgcn_mfma_f32_16x16x32_bf16(a, B[ks][ct], acc[ct], 0, 0, 0);
        }
#pragma unroll
        for (int ct = 0; ct < 2; ++ct) {
            int c = cb + ct * 16 + m;
#pragma unroll
            for (int i = 0; i < 4; ++i) {
                int rr = r0 + q * 4 + i;
                if (op == 0) y[(size_t)rr * 64 + c] = f2bf(acc[ct][i]);
                else         r[(size_t)rr * 64 + c] = acc[ct][i] + b2f[c];
            }
        }
    }
}

// ---------------- agg2y: z = mean(y over neighbors) + r ; z f32 (out) + bf16 (zb) ----------------
__global__ __launch_bounds__(256) void k_agg2y(const ushort_t* __restrict__ y, const int* __restrict__ rowptr,
                                               const ushort_t* __restrict__ srclist, const float* __restrict__ r,
                                               float* __restrict__ zf, ushort_t* __restrict__ zb) {
    int node = (blockIdx.x * 256 + threadIdx.x) >> 6;
    int lane = threadIdx.x & 63;
    if (node >= NN) return;
    int half = lane >> 5, l32 = lane & 31;
    int beg = rowptr[node], end = rowptr[node + 1];
    float a0 = 0.f, a1 = 0.f;
    int j = beg + half;
    for (; j + 2 < end; j += 4) {
        int s0 = srclist[j], s1 = srclist[j + 2];
        uint32_t p0 = *reinterpret_cast<const uint32_t*>(y + (size_t)s0 * 64 + l32 * 2);
        uint32_t p1 = *reinterpret_cast<const uint32_t*>(y + (size_t)s1 * 64 + l32 * 2);
        a0 += bf2f((uint16_t)(p0 & 0xffff)) + bf2f((uint16_t)(p1 & 0xffff));
        a1 += bf2f((uint16_t)(p0 >> 16)) + bf2f((uint16_t)(p1 >> 16));
    }
    for (; j < end; j += 2) {
        int s = srclist[j];
        uint32_t p = *reinterpret_cast<const uint32_t*>(y + (size_t)s * 64 + l32 * 2);
        a0 += bf2f((uint16_t)(p & 0xffff));
        a1 += bf2f((uint16_t)(p >> 16));
    }
    a0 += __shfl_xor(a0, 32);
    a1 += __shfl_xor(a1, 32);
    if (half == 0) {
        float inv = 1.0f / (float)max(end - beg, 1);
        float2 rv = *reinterpret_cast<const float2*>(r + (size_t)node * 64 + l32 * 2);
        float z0 = a0 * inv + rv.x;
        float z1 = a1 * inv + rv.y;
        float2 zo; zo.x = z0; zo.y = z1;
        *reinterpret_cast<float2*>(zf + (size_t)node * 64 + l32 * 2) = zo;
        uint32_t o = (uint32_t)f2bf(z0) | ((uint32_t)f2bf(z1) << 16);
        *reinterpret_cast<uint32_t*>(zb + (size_t)node * 64 + l32 * 2) = o;
    }
}

// ---------------- GEMM3 (persistent-B): x_hat = zb @ wdt^T + bd -> f32 ----------------
__global__ __launch_bounds__(256, 2) void k_gemm3p(const ushort_t* __restrict__ zb, const ushort_t* __restrict__ wdt,
                                                   const float* __restrict__ bdf, float* __restrict__ xhat) {
    int wv = threadIdx.x >> 6, lane = threadIdx.x & 63;
    int m = lane & 15, q = lane >> 4;
    bf16x8 B[2][2];
#pragma unroll
    for (int ks = 0; ks < 2; ++ks) {
        int kb = ks * 32 + q * 8;
#pragma unroll
        for (int ct = 0; ct < 2; ++ct)
            B[ks][ct] = *reinterpret_cast<const bf16x8*>(wdt + (size_t)(wv * 32 + ct * 16 + m) * 64 + kb);
    }
    const int ntiles = NN / 16;
    for (int t = blockIdx.x; t < ntiles; t += gridDim.x) {
        int r0 = t * 16;
        int row = r0 + m;
        f32x4 acc[2];
        acc[0] = (f32x4){0.f, 0.f, 0.f, 0.f}; acc[1] = acc[0];
#pragma unroll
        for (int ks = 0; ks < 2; ++ks) {
            int kb = ks * 32 + q * 8;
            bf16x8 a = *reinterpret_cast<const bf16x8*>(zb + (size_t)row * 64 + kb);
#pragma unroll
            for (int ct = 0; ct < 2; ++ct)
                acc[ct] = __builtin_amdgcn_mfma_f32_16x16x32_bf16(a, B[ks][ct], acc[ct], 0, 0, 0);
        }
#pragma unroll
        for (int ct = 0; ct < 2; ++ct) {
            int c = wv * 32 + ct * 16 + m;
            float bias = bdf[c];
#pragma unroll
            for (int i = 0; i < 4; ++i) {
                int rr = r0 + q * 4 + i;
                xhat[(size_t)rr * 128 + c] = acc[ct][i] + bias;
            }
        }
    }
}

extern "C" void kernel_launch(void* const* d_in, const int* in_sizes, int n_in,
                              void* d_out, int out_size, void* d_ws, size_t ws_size,
                              hipStream_t stream) {
    // ---- order-agnostic input identification by element count ----
    const void *px = nullptr, *pei = nullptr, *pW1l = nullptr, *pW1r = nullptr,
               *pW2l = nullptr, *pW2r = nullptr, *pWd = nullptr,
               *pb1 = nullptr, *pb2 = nullptr, *pbd = nullptr;
    for (int i = 0; i < n_in; ++i) {
        const void* p = d_in[i];
        switch (in_sizes[i]) {
            case 6400000: px  = p; break;
            case 1600000: pei = p; break;
            case 32768:   if (!pW1l) pW1l = p; else pW1r = p; break;
            case 16384:   if (!pW2l) pW2l = p; else pW2r = p; break;
            case 8192:    pWd = p; break;
            case 256:     pb1 = p; break;
            case 128:     pbd = p; break;
            case 64:      pb2 = p; break;
            default: break;
        }
    }
    if (!px || !pei || !pW1l || !pW1r || !pW2l || !pW2r || !pWd || !pb1 || !pb2 || !pbd) {
        px = d_in[0]; pei = d_in[1]; pW1l = d_in[2]; pb1 = d_in[3]; pW1r = d_in[4];
        pW2l = d_in[5]; pb2 = d_in[6]; pW2r = d_in[7]; pWd = d_in[8]; pbd = d_in[9];
    }
    const int* ei = (const int*)pei;

    // ---- workspace (~40 MB) ----
    char* base = (char*)d_ws;
    size_t off = 0;
    auto alloc = [&](size_t bytes) -> void* {
        void* r = base + off;
        off = (off + bytes + 255) & ~(size_t)255;
        return r;
    };
    int* mode     = (int*)alloc(4);
    int* fmode    = (int*)alloc(4);
    int* rowptr   = (int*)alloc((size_t)(NN + 1) * 4);
    int* blocksum = (int*)alloc((size_t)NB * 4);
    int* blockoff = (int*)alloc((size_t)NB * 4);
    ushort_t* srclist = (ushort_t*)alloc((size_t)NE * 2);   // uint16 node ids
    ushort_t* wt   = (ushort_t*)alloc((size_t)65536 * 2);
    ushort_t* w2lt = (ushort_t*)alloc((size_t)16384 * 2);
    ushort_t* w2rt = (ushort_t*)alloc((size_t)16384 * 2);
    ushort_t* wdt  = (ushort_t*)alloc((size_t)8192 * 2);
    float* b1f    = (float*)alloc(256 * 4);
    float* b2f    = (float*)alloc(64 * 4);
    float* bdf    = (float*)alloc(128 * 4);
    ushort_t* xb  = (ushort_t*)alloc((size_t)NN * 128 * 2);   // dead after gemm1
    ushort_t* h   = (ushort_t*)alloc((size_t)NN * 256 * 2);   // written by gemm1 (late)

    // padded counters alias the h region (dead until gemm1): cnt [0,6.4MB), cursor [6.4,12.8MB)
    int* cnt    = (int*)h;                                    // NN*CS ints = 6.4MB
    int* cursor = (int*)((char*)h + (size_t)NN * CS * 4);     // NN*CS ints = 6.4MB

    // outputs f32: z [NN,64] then x_hat [NN,128]
    float* out_z    = (float*)d_out;
    float* out_xhat = out_z + (size_t)NN * 64;

    // aliases:
    ushort_t* meanx = (ushort_t*)out_xhat;                       // [NN,128] bf16, dead after gemm1
    float*    rbuf  = (float*)((char*)out_xhat + (size_t)NN * 128 * 2); // [NN,64] f32, dead before gemm3
    ushort_t* y     = xb;                                        // [NN,64] bf16 (xb dead after gemm1)
    ushort_t* zb    = xb + (size_t)NN * 64;                      // [NN,64] bf16

    hipMemsetAsync(cnt, 0, (size_t)NN * CS * 4, stream);

    k_modes<<<1, 256, 0, stream>>>(ei, (const ushort_t*)px, mode, fmode);

    int eb = (NE + 255) / 256;
    k_degree<<<eb, 256, 0, stream>>>(ei, mode, cnt);
    k_scanA<<<NB, 256, 0, stream>>>(cnt, rowptr, blocksum);
    k_scanB<<<1, 256, 0, stream>>>(blocksum, blockoff, rowptr);
    k_scanC<<<NB, 256, 0, stream>>>(rowptr, blockoff, cursor);
    k_fill<<<eb, 256, 0, stream>>>(ei, mode, cursor, srclist);

    k_cvt<<<(NN * 128 / 4 + 255) / 256, 256, 0, stream>>>(px, fmode, xb);
    k_prep3<<<418, 256, 0, stream>>>(pW1l, pW1r, pW2l, pW2r, pWd, pb1, pb2, pbd, fmode,
                                     wt, w2lt, w2rt, wdt, b1f, b2f, bdf);

    int ab = (NN + 3) / 4;                     // 12500 blocks, 4 waves each
    k_agg128<<<ab, 256, 0, stream>>>(xb, rowptr, srclist, meanx);

    k_gemm1p<<<512, 256, 0, stream>>>(meanx, xb, wt, b1f, h);
    k_gemm2p<<<512, 256, 0, stream>>>(h, w2lt, w2rt, b2f, y, rbuf);
    k_agg2y<<<ab, 256, 0, stream>>>(y, rowptr, srclist, rbuf, out_z, zb);
    k_gemm3p<<<512, 256, 0, stream>>>(zb, wdt, bdf, out_xhat);
}

// Round 12
// 267.174 us; speedup vs baseline: 2.8804x; 1.1815x over previous
//
#include <hip/hip_runtime.h>
#include <stdint.h>

#define NN 50000
#define NE 800000
#define NB 196     // scan blocks over nodes: (NN+255)/256
#define NBK 196    // edge chunks: (NE+4095)/4096
#define NBUK 196   // dst buckets of 256 nodes
#define CHK 4096   // edges per chunk
#define MTOT (NBUK * NBK)   // 38416
#define MSB 151    // scan blocks over MTOT: (MTOT+255)/256
// IN=128, HID=256, LAT=64

typedef __bf16 bf16x8 __attribute__((ext_vector_type(8)));
typedef float f32x4 __attribute__((ext_vector_type(4)));
typedef unsigned short ushort_t;

__device__ inline float bf2f(uint16_t u) {
    union { uint32_t i; float f; } v; v.i = ((uint32_t)u) << 16; return v.f;
}
__device__ inline uint16_t f2bf(float f) {
    uint32_t u = __float_as_uint(f);
    u += 0x7fffu + ((u >> 16) & 1u);
    return (uint16_t)(u >> 16);
}
__device__ inline float rdf(const void* p, int i, int bf) {
    return bf ? bf2f(((const ushort_t*)p)[i]) : ((const float*)p)[i];
}

// ---------------- combined mode detection: edge dtype + float dtype ----------------
__global__ __launch_bounds__(256) void k_modes(const int* __restrict__ ei, const ushort_t* __restrict__ xw,
                                               int* __restrict__ mode, int* __restrict__ fmode) {
    __shared__ int nz, bad;
    if (threadIdx.x == 0) { nz = 0; bad = 0; }
    __syncthreads();
    int t = threadIdx.x;
    int v = ei[2 * t + 1] | ei[2 * (t + 256) + 1] | ei[2 * (t + 512) + 1] | ei[2 * (t + 768) + 1];
    if (v) atomicOr(&nz, 1);
#pragma unroll
    for (int r = 0; r < 2; ++r) {
        uint16_t w = xw[t + 256 * r];
        int e = (w >> 7) & 0xFF;
        if (!(w == 0 || (e >= 96 && e <= 144))) atomicOr(&bad, 1);
    }
    __syncthreads();
    if (t == 0) { *mode = (nz == 0) ? 1 : 0; *fmode = (bad == 0) ? 1 : 0; }
}

// ---------------- bucket sort phase A: per-chunk LDS histogram over 196 coarse buckets ----------------
__global__ __launch_bounds__(256) void k_histA(const int* __restrict__ ei, const int* __restrict__ mode,
                                               int* __restrict__ cntm) {
    __shared__ int hist[NBUK];
    int t = threadIdx.x, blk = blockIdx.x;
    if (t < NBUK) hist[t] = 0;
    __syncthreads();
    int sh = *mode;
    for (int i = t; i < CHK; i += 256) {
        int e = blk * CHK + i;
        if (e < NE) {
            int d = ei[(size_t)(NE + e) << sh];
            atomicAdd(&hist[d >> 8], 1);
        }
    }
    __syncthreads();
    if (t < NBUK) cntm[t * NBK + blk] = hist[t];
}

// ---------------- generic 3-phase scan helpers ----------------
__device__ inline int block_scan256(int v, int* ws, int* btot) {
    int lane = threadIdx.x & 63, wv = threadIdx.x >> 6;
    int incl = v;
#pragma unroll
    for (int d = 1; d < 64; d <<= 1) {
        int n = __shfl_up(incl, d);
        if (lane >= d) incl += n;
    }
    if (lane == 63) ws[wv] = incl;
    __syncthreads();
    if (threadIdx.x == 0) {
        int r = 0;
#pragma unroll
        for (int k = 0; k < 4; ++k) { int t = ws[k]; ws[k] = r; r += t; }
        *btot = r;
    }
    __syncthreads();
    return ws[wv] + incl - v;
}

// scan over cntm[MTOT] -> offm
__global__ __launch_bounds__(256) void k_scanMA(const int* __restrict__ cntm, int* __restrict__ offm,
                                                int* __restrict__ bsM) {
    __shared__ int ws[4]; __shared__ int btot;
    int i = blockIdx.x * 256 + threadIdx.x;
    int v = (i < MTOT) ? cntm[i] : 0;
    int excl = block_scan256(v, ws, &btot);
    if (i < MTOT) offm[i] = excl;
    if (threadIdx.x == 0) bsM[blockIdx.x] = btot;
}
__global__ __launch_bounds__(256) void k_scanMB(const int* __restrict__ bsM, int* __restrict__ boM) {
    __shared__ int ws[4]; __shared__ int btot;
    int t = threadIdx.x;
    int v = (t < MSB) ? bsM[t] : 0;
    int excl = block_scan256(v, ws, &btot);
    if (t < MSB) boM[t] = excl;
}
__global__ __launch_bounds__(256) void k_scanMC(int* __restrict__ offm, const int* __restrict__ boM) {
    int i = blockIdx.x * 256 + threadIdx.x;
    if (i < MTOT) offm[i] += boM[blockIdx.x];
}

// ---------------- phase C: scatter edges into bucket-sorted pairs (LDS cursors, no global atomics) ----------------
__global__ __launch_bounds__(256) void k_scatterC(const int* __restrict__ ei, const int* __restrict__ mode,
                                                  const int* __restrict__ offm, uint32_t* __restrict__ pairs) {
    __shared__ int cur[NBUK];
    int t = threadIdx.x, blk = blockIdx.x;
    if (t < NBUK) cur[t] = offm[t * NBK + blk];
    __syncthreads();
    int sh = *mode;
    for (int i = t; i < CHK; i += 256) {
        int e = blk * CHK + i;
        if (e < NE) {
            int s = ei[(size_t)e << sh];
            int d = ei[(size_t)(NE + e) << sh];
            int pos = atomicAdd(&cur[d >> 8], 1);
            pairs[pos] = (uint32_t)s | ((uint32_t)(d & 255) << 16);
        }
    }
}

// ---------------- phase D1: per-bucket degree count (no atomics to global) ----------------
__global__ __launch_bounds__(256) void k_d1(const uint32_t* __restrict__ pairs, const int* __restrict__ offm,
                                            int* __restrict__ deg) {
    __shared__ int hist[256];
    int t = threadIdx.x, b = blockIdx.x;
    hist[t] = 0;
    __syncthreads();
    int beg = offm[b * NBK];
    int end = (b + 1 < NBUK) ? offm[(b + 1) * NBK] : NE;
    for (int i = beg + t; i < end; i += 256) {
        uint32_t p = pairs[i];
        atomicAdd(&hist[p >> 16], 1);
    }
    __syncthreads();
    int node = b * 256 + t;
    if (node < NN) deg[node] = hist[t];
}

// scan over deg[NN] -> rowptr
__global__ __launch_bounds__(256) void k_scanA(const int* __restrict__ deg, int* __restrict__ rowptr,
                                               int* __restrict__ blocksum) {
    __shared__ int ws[4]; __shared__ int btot;
    int i = blockIdx.x * 256 + threadIdx.x;
    int v = (i < NN) ? deg[i] : 0;
    int excl = block_scan256(v, ws, &btot);
    if (i < NN) rowptr[i] = excl;
    if (threadIdx.x == 0) blocksum[blockIdx.x] = btot;
}
__global__ __launch_bounds__(256) void k_scanB(const int* __restrict__ blocksum, int* __restrict__ blockoff,
                                               int* __restrict__ rowptr) {
    __shared__ int ws[4]; __shared__ int btot;
    int t = threadIdx.x;
    int v = (t < NB) ? blocksum[t] : 0;
    int excl = block_scan256(v, ws, &btot);
    if (t < NB) blockoff[t] = excl;
    if (t == NB - 1) rowptr[NN] = excl + v;
}
__global__ __launch_bounds__(256) void k_scanC(int* __restrict__ rowptr, const int* __restrict__ blockoff) {
    int i = blockIdx.x * 256 + threadIdx.x;
    if (i < NN) rowptr[i] += blockoff[blockIdx.x];
}

// ---------------- phase D2: per-bucket fine scatter into srclist (LDS cursors, 32KB window) ----------------
__global__ __launch_bounds__(256) void k_d2(const uint32_t* __restrict__ pairs, const int* __restrict__ offm,
                                            const int* __restrict__ rowptr, ushort_t* __restrict__ srclist) {
    __shared__ int cur[256];
    int t = threadIdx.x, b = blockIdx.x;
    int node = b * 256 + t;
    cur[t] = (node < NN) ? rowptr[node] : 0;
    __syncthreads();
    int beg = offm[b * NBK];
    int end = (b + 1 < NBUK) ? offm[(b + 1) * NBK] : NE;
    for (int i = beg + t; i < end; i += 256) {
        uint32_t p = pairs[i];
        int pos = atomicAdd(&cur[p >> 16], 1);
        srclist[pos] = (ushort_t)(p & 0xffff);
    }
}

// ---------------- x -> bf16 workspace copy ----------------
__global__ __launch_bounds__(256) void k_cvt(const void* __restrict__ x, const int* __restrict__ fmode,
                                             ushort_t* __restrict__ xb) {
    int i = blockIdx.x * 256 + threadIdx.x;
    const int total = NN * 128 / 4;
    if (i >= total) return;
    if (*fmode) {
        reinterpret_cast<ushort4*>(xb)[i] = reinterpret_cast<const ushort4*>(x)[i];
    } else {
        float4 v = reinterpret_cast<const float4*>(x)[i];
        ushort4 o;
        o.x = f2bf(v.x); o.y = f2bf(v.y); o.z = f2bf(v.z); o.w = f2bf(v.w);
        reinterpret_cast<ushort4*>(xb)[i] = o;
    }
}

// ---------------- weight prep: transposed bf16 for MFMA B-operand ----------------
__global__ __launch_bounds__(256) void k_prep3(const void* __restrict__ W1l, const void* __restrict__ W1r,
                                               const void* __restrict__ W2l, const void* __restrict__ W2r,
                                               const void* __restrict__ Wd,
                                               const void* __restrict__ b1, const void* __restrict__ b2,
                                               const void* __restrict__ bd,
                                               const int* __restrict__ fmode,
                                               ushort_t* __restrict__ wt, ushort_t* __restrict__ w2lt,
                                               ushort_t* __restrict__ w2rt, ushort_t* __restrict__ wdt,
                                               float* __restrict__ b1f, float* __restrict__ b2f,
                                               float* __restrict__ bdf) {
    int idx = blockIdx.x * 256 + threadIdx.x;
    int bf = *fmode;
    if (idx < 65536) {
        int c = idx >> 8, k = idx & 255;
        float v = (k < 128) ? rdf(W1l, k * 256 + c, bf) : rdf(W1r, (k - 128) * 256 + c, bf);
        wt[c * 256 + k] = f2bf(v);
    } else if (idx < 81920) {
        int t = idx - 65536;
        int c = t >> 8, k = t & 255;
        w2lt[c * 256 + k] = f2bf(rdf(W2l, k * 64 + c, bf));
    } else if (idx < 98304) {
        int t = idx - 81920;
        int c = t >> 8, k = t & 255;
        w2rt[c * 256 + k] = f2bf(rdf(W2r, k * 64 + c, bf));
    } else if (idx < 106496) {
        int t = idx - 98304;
        int c = t >> 6, k = t & 63;
        wdt[c * 64 + k] = f2bf(rdf(Wd, k * 128 + c, bf));
    } else if (idx < 106752) {
        b1f[idx - 106496] = rdf(b1, idx - 106496, bf);
    } else if (idx < 106816) {
        b2f[idx - 106752] = rdf(b2, idx - 106752, bf);
    } else if (idx < 106944) {
        bdf[idx - 106816] = rdf(bd, idx - 106816, bf);
    }
}

// ---------------- agg1: meanx = mean of x rows (one wave/node, 4-way edge unroll) ----------------
__global__ __launch_bounds__(256) void k_agg128(const ushort_t* __restrict__ xb, const int* __restrict__ rowptr,
                                                const ushort_t* __restrict__ srclist, ushort_t* __restrict__ out) {
    int node = (blockIdx.x * 256 + threadIdx.x) >> 6;
    int lane = threadIdx.x & 63;
    if (node >= NN) return;
    int beg = rowptr[node], end = rowptr[node + 1];
    float a0 = 0.f, a1 = 0.f;
    int j = beg;
    for (; j + 3 < end; j += 4) {
        int s0 = srclist[j], s1 = srclist[j + 1], s2 = srclist[j + 2], s3 = srclist[j + 3];
        uint32_t p0 = *reinterpret_cast<const uint32_t*>(xb + (size_t)s0 * 128 + lane * 2);
        uint32_t p1 = *reinterpret_cast<const uint32_t*>(xb + (size_t)s1 * 128 + lane * 2);
        uint32_t p2 = *reinterpret_cast<const uint32_t*>(xb + (size_t)s2 * 128 + lane * 2);
        uint32_t p3 = *reinterpret_cast<const uint32_t*>(xb + (size_t)s3 * 128 + lane * 2);
        a0 += bf2f((uint16_t)(p0 & 0xffff)) + bf2f((uint16_t)(p1 & 0xffff))
            + bf2f((uint16_t)(p2 & 0xffff)) + bf2f((uint16_t)(p3 & 0xffff));
        a1 += bf2f((uint16_t)(p0 >> 16)) + bf2f((uint16_t)(p1 >> 16))
            + bf2f((uint16_t)(p2 >> 16)) + bf2f((uint16_t)(p3 >> 16));
    }
    for (; j < end; ++j) {
        int s = srclist[j];
        uint32_t p = *reinterpret_cast<const uint32_t*>(xb + (size_t)s * 128 + lane * 2);
        a0 += bf2f((uint16_t)(p & 0xffff));
        a1 += bf2f((uint16_t)(p >> 16));
    }
    float inv = 1.0f / (float)max(end - beg, 1);
    uint32_t o = (uint32_t)f2bf(a0 * inv) | ((uint32_t)f2bf(a1 * inv) << 16);
    *reinterpret_cast<uint32_t*>(out + (size_t)node * 128 + lane * 2) = o;
}

// ---------------- GEMM1 (persistent-B MFMA): h = relu([meanx|xb] @ wt^T + b1) ----------------
__global__ __launch_bounds__(256, 2) void k_gemm1p(const ushort_t* __restrict__ meanx, const ushort_t* __restrict__ xb,
                                                   const ushort_t* __restrict__ wt, const float* __restrict__ b1f,
                                                   ushort_t* __restrict__ h) {
    int wv = threadIdx.x >> 6, lane = threadIdx.x & 63;
    int m = lane & 15, q = lane >> 4;
    bf16x8 B[8][4];
#pragma unroll
    for (int ks = 0; ks < 8; ++ks) {
        int kb = ks * 32 + q * 8;
#pragma unroll
        for (int ct = 0; ct < 4; ++ct)
            B[ks][ct] = *reinterpret_cast<const bf16x8*>(wt + (size_t)(wv * 64 + ct * 16 + m) * 256 + kb);
    }
    const int ntiles = NN / 16;
    for (int t = blockIdx.x; t < ntiles; t += gridDim.x) {
        int r0 = t * 16;
        int row = r0 + m;
        f32x4 acc[4];
#pragma unroll
        for (int ct = 0; ct < 4; ++ct) acc[ct] = (f32x4){0.f, 0.f, 0.f, 0.f};
#pragma unroll
        for (int ks = 0; ks < 8; ++ks) {
            int kb = ks * 32 + q * 8;
            const ushort_t* ap = (ks < 4) ? (meanx + (size_t)row * 128 + kb)
                                          : (xb + (size_t)row * 128 + (kb - 128));
            bf16x8 a = *reinterpret_cast<const bf16x8*>(ap);
#pragma unroll
            for (int ct = 0; ct < 4; ++ct)
                acc[ct] = __builtin_amdgcn_mfma_f32_16x16x32_bf16(a, B[ks][ct], acc[ct], 0, 0, 0);
        }
#pragma unroll
        for (int ct = 0; ct < 4; ++ct) {
            int c = wv * 64 + ct * 16 + m;
            float bias = b1f[c];
#pragma unroll
            for (int i = 0; i < 4; ++i) {
                int rr = r0 + q * 4 + i;
                h[(size_t)rr * 256 + c] = f2bf(fmaxf(acc[ct][i] + bias, 0.f));
            }
        }
    }
}

// ---------------- GEMM2 (persistent-B): y = h@W2l (bf16), r = h@W2r + b2 (f32) ----------------
__global__ __launch_bounds__(256, 2) void k_gemm2p(const ushort_t* __restrict__ h,
                                                   const ushort_t* __restrict__ w2lt, const ushort_t* __restrict__ w2rt,
                                                   const float* __restrict__ b2f,
                                                   ushort_t* __restrict__ y, float* __restrict__ r) {
    int wv = threadIdx.x >> 6, lane = threadIdx.x & 63;
    int m = lane & 15, q = lane >> 4;
    int op = wv >> 1;
    int cb = (wv & 1) * 32;
    const ushort_t* wtx = op ? w2rt : w2lt;
    bf16x8 B[8][2];
#pragma unroll
    for (int ks = 0; ks < 8; ++ks) {
        int kb = ks * 32 + q * 8;
#pragma unroll
        for (int ct = 0; ct < 2; ++ct)
            B[ks][ct] = *reinterpret_cast<const bf16x8*>(wtx + (size_t)(cb + ct * 16 + m) * 256 + kb);
    }
    const int ntiles = NN / 16;
    for (int t = blockIdx.x; t < ntiles; t += gridDim.x) {
        int r0 = t * 16;
        int row = r0 + m;
        f32x4 acc[2];
        acc[0] = (f32x4){0.f, 0.f, 0.f, 0.f}; acc[1] = acc[0];
#pragma unroll
        for (int ks = 0; ks < 8; ++ks) {
            int kb = ks * 32 + q * 8;
            bf16x8 a = *reinterpret_cast<const bf16x8*>(h + (size_t)row * 256 + kb);
#pragma unroll
            for (int ct = 0; ct < 2; ++ct)
                acc[ct] = __builtin_amdgcn_mfma_f32_16x16x32_bf16(a, B[ks][ct], acc[ct], 0, 0, 0);
        }
#pragma unroll
        for (int ct = 0; ct < 2; ++ct) {
            int c = cb + ct * 16 + m;
#pragma unroll
            for (int i = 0; i < 4; ++i) {
                int rr = r0 + q * 4 + i;
                if (op == 0) y[(size_t)rr * 64 + c] = f2bf(acc[ct][i]);
                else         r[(size_t)rr * 64 + c] = acc[ct][i] + b2f[c];
            }
        }
    }
}

// ---------------- agg2y: z = mean(y over neighbors) + r ; z f32 (out) + bf16 (zb) ----------------
__global__ __launch_bounds__(256) void k_agg2y(const ushort_t* __restrict__ y, const int* __restrict__ rowptr,
                                               const ushort_t* __restrict__ srclist, const float* __restrict__ r,
                                               float* __restrict__ zf, ushort_t* __restrict__ zb) {
    int node = (blockIdx.x * 256 + threadIdx.x) >> 6;
    int lane = threadIdx.x & 63;
    if (node >= NN) return;
    int half = lane >> 5, l32 = lane & 31;
    int beg = rowptr[node], end = rowptr[node + 1];
    float a0 = 0.f, a1 = 0.f;
    int j = beg + half;
    for (; j + 2 < end; j += 4) {
        int s0 = srclist[j], s1 = srclist[j + 2];
        uint32_t p0 = *reinterpret_cast<const uint32_t*>(y + (size_t)s0 * 64 + l32 * 2);
        uint32_t p1 = *reinterpret_cast<const uint32_t*>(y + (size_t)s1 * 64 + l32 * 2);
        a0 += bf2f((uint16_t)(p0 & 0xffff)) + bf2f((uint16_t)(p1 & 0xffff));
        a1 += bf2f((uint16_t)(p0 >> 16)) + bf2f((uint16_t)(p1 >> 16));
    }
    for (; j < end; j += 2) {
        int s = srclist[j];
        uint32_t p = *reinterpret_cast<const uint32_t*>(y + (size_t)s * 64 + l32 * 2);
        a0 += bf2f((uint16_t)(p & 0xffff));
        a1 += bf2f((uint16_t)(p >> 16));
    }
    a0 += __shfl_xor(a0, 32);
    a1 += __shfl_xor(a1, 32);
    if (half == 0) {
        float inv = 1.0f / (float)max(end - beg, 1);
        float2 rv = *reinterpret_cast<const float2*>(r + (size_t)node * 64 + l32 * 2);
        float z0 = a0 * inv + rv.x;
        float z1 = a1 * inv + rv.y;
        float2 zo; zo.x = z0; zo.y = z1;
        *reinterpret_cast<float2*>(zf + (size_t)node * 64 + l32 * 2) = zo;
        uint32_t o = (uint32_t)f2bf(z0) | ((uint32_t)f2bf(z1) << 16);
        *reinterpret_cast<uint32_t*>(zb + (size_t)node * 64 + l32 * 2) = o;
    }
}

// ---------------- GEMM3 (persistent-B): x_hat = zb @ wdt^T + bd -> f32 ----------------
__global__ __launch_bounds__(256, 2) void k_gemm3p(const ushort_t* __restrict__ zb, const ushort_t* __restrict__ wdt,
                                                   const float* __restrict__ bdf, float* __restrict__ xhat) {
    int wv = threadIdx.x >> 6, lane = threadIdx.x & 63;
    int m = lane & 15, q = lane >> 4;
    bf16x8 B[2][2];
#pragma unroll
    for (int ks = 0; ks < 2; ++ks) {
        int kb = ks * 32 + q * 8;
#pragma unroll
        for (int ct = 0; ct < 2; ++ct)
            B[ks][ct] = *reinterpret_cast<const bf16x8*>(wdt + (size_t)(wv * 32 + ct * 16 + m) * 64 + kb);
    }
    const int ntiles = NN / 16;
    for (int t = blockIdx.x; t < ntiles; t += gridDim.x) {
        int r0 = t * 16;
        int row = r0 + m;
        f32x4 acc[2];
        acc[0] = (f32x4){0.f, 0.f, 0.f, 0.f}; acc[1] = acc[0];
#pragma unroll
        for (int ks = 0; ks < 2; ++ks) {
            int kb = ks * 32 + q * 8;
            bf16x8 a = *reinterpret_cast<const bf16x8*>(zb + (size_t)row * 64 + kb);
#pragma unroll
            for (int ct = 0; ct < 2; ++ct)
                acc[ct] = __builtin_amdgcn_mfma_f32_16x16x32_bf16(a, B[ks][ct], acc[ct], 0, 0, 0);
        }
#pragma unroll
        for (int ct = 0; ct < 2; ++ct) {
            int c = wv * 32 + ct * 16 + m;
            float bias = bdf[c];
#pragma unroll
            for (int i = 0; i < 4; ++i) {
                int rr = r0 + q * 4 + i;
                xhat[(size_t)rr * 128 + c] = acc[ct][i] + bias;
            }
        }
    }
}

extern "C" void kernel_launch(void* const* d_in, const int* in_sizes, int n_in,
                              void* d_out, int out_size, void* d_ws, size_t ws_size,
                              hipStream_t stream) {
    // ---- order-agnostic input identification by element count ----
    const void *px = nullptr, *pei = nullptr, *pW1l = nullptr, *pW1r = nullptr,
               *pW2l = nullptr, *pW2r = nullptr, *pWd = nullptr,
               *pb1 = nullptr, *pb2 = nullptr, *pbd = nullptr;
    for (int i = 0; i < n_in; ++i) {
        const void* p = d_in[i];
        switch (in_sizes[i]) {
            case 6400000: px  = p; break;
            case 1600000: pei = p; break;
            case 32768:   if (!pW1l) pW1l = p; else pW1r = p; break;
            case 16384:   if (!pW2l) pW2l = p; else pW2r = p; break;
            case 8192:    pWd = p; break;
            case 256:     pb1 = p; break;
            case 128:     pbd = p; break;
            case 64:      pb2 = p; break;
            default: break;
        }
    }
    if (!px || !pei || !pW1l || !pW1r || !pW2l || !pW2r || !pWd || !pb1 || !pb2 || !pbd) {
        px = d_in[0]; pei = d_in[1]; pW1l = d_in[2]; pb1 = d_in[3]; pW1r = d_in[4];
        pW2l = d_in[5]; pb2 = d_in[6]; pW2r = d_in[7]; pWd = d_in[8]; pbd = d_in[9];
    }
    const int* ei = (const int*)pei;

    // ---- workspace ----
    char* base = (char*)d_ws;
    size_t off = 0;
    auto alloc = [&](size_t bytes) -> void* {
        void* r = base + off;
        off = (off + bytes + 255) & ~(size_t)255;
        return r;
    };
    int* mode     = (int*)alloc(4);
    int* fmode    = (int*)alloc(4);
    int* rowptr   = (int*)alloc((size_t)(NN + 1) * 4);
    int* blocksum = (int*)alloc((size_t)NB * 4);
    int* blockoff = (int*)alloc((size_t)NB * 4);
    int* cntm     = (int*)alloc((size_t)MTOT * 4);
    int* offm     = (int*)alloc((size_t)MTOT * 4);
    int* bsM      = (int*)alloc(256 * 4);
    int* boM      = (int*)alloc(256 * 4);
    ushort_t* srclist = (ushort_t*)alloc((size_t)NE * 2);   // uint16 node ids
    ushort_t* wt   = (ushort_t*)alloc((size_t)65536 * 2);
    ushort_t* w2lt = (ushort_t*)alloc((size_t)16384 * 2);
    ushort_t* w2rt = (ushort_t*)alloc((size_t)16384 * 2);
    ushort_t* wdt  = (ushort_t*)alloc((size_t)8192 * 2);
    float* b1f    = (float*)alloc(256 * 4);
    float* b2f    = (float*)alloc(64 * 4);
    float* bdf    = (float*)alloc(128 * 4);
    ushort_t* xb  = (ushort_t*)alloc((size_t)NN * 128 * 2);   // dead after gemm1
    ushort_t* h   = (ushort_t*)alloc((size_t)NN * 256 * 2);   // written by gemm1 (late)

    // sort scratch aliases the h region (dead until gemm1p):
    uint32_t* pairs = (uint32_t*)h;                          // NE*4 = 3.2MB
    int* deg        = (int*)((char*)h + (size_t)NE * 4 + 256); // NN*4 = 200KB

    // outputs f32: z [NN,64] then x_hat [NN,128]
    float* out_z    = (float*)d_out;
    float* out_xhat = out_z + (size_t)NN * 64;

    // aliases:
    ushort_t* meanx = (ushort_t*)out_xhat;                       // [NN,128] bf16, dead after gemm1
    float*    rbuf  = (float*)((char*)out_xhat + (size_t)NN * 128 * 2); // [NN,64] f32, dead before gemm3
    ushort_t* y     = xb;                                        // [NN,64] bf16 (xb dead after gemm1)
    ushort_t* zb    = xb + (size_t)NN * 64;                      // [NN,64] bf16

    k_modes<<<1, 256, 0, stream>>>(ei, (const ushort_t*)px, mode, fmode);

    // ---- CSR build via two-level bucket sort (no global atomics) ----
    k_histA<<<NBK, 256, 0, stream>>>(ei, mode, cntm);
    k_scanMA<<<MSB, 256, 0, stream>>>(cntm, offm, bsM);
    k_scanMB<<<1, 256, 0, stream>>>(bsM, boM);
    k_scanMC<<<MSB, 256, 0, stream>>>(offm, boM);
    k_scatterC<<<NBK, 256, 0, stream>>>(ei, mode, offm, pairs);
    k_d1<<<NBUK, 256, 0, stream>>>(pairs, offm, deg);
    k_scanA<<<NB, 256, 0, stream>>>(deg, rowptr, blocksum);
    k_scanB<<<1, 256, 0, stream>>>(blocksum, blockoff, rowptr);
    k_scanC<<<NB, 256, 0, stream>>>(rowptr, blockoff);
    k_d2<<<NBUK, 256, 0, stream>>>(pairs, offm, rowptr, srclist);

    k_cvt<<<(NN * 128 / 4 + 255) / 256, 256, 0, stream>>>(px, fmode, xb);
    k_prep3<<<418, 256, 0, stream>>>(pW1l, pW1r, pW2l, pW2r, pWd, pb1, pb2, pbd, fmode,
                                     wt, w2lt, w2rt, wdt, b1f, b2f, bdf);

    int ab = (NN + 3) / 4;                     // 12500 blocks, 4 waves each
    k_agg128<<<ab, 256, 0, stream>>>(xb, rowptr, srclist, meanx);

    k_gemm1p<<<512, 256, 0, stream>>>(meanx, xb, wt, b1f, h);
    k_gemm2p<<<512, 256, 0, stream>>>(h, w2lt, w2rt, b2f, y, rbuf);
    k_agg2y<<<ab, 256, 0, stream>>>(y, rowptr, srclist, rbuf, out_z, zb);
    k_gemm3p<<<512, 256, 0, stream>>>(zb, wdt, bdf, out_xhat);
}

// Round 13
// 254.185 us; speedup vs baseline: 3.0276x; 1.0511x over previous
//
#include <hip/hip_runtime.h>
#include <stdint.h>

#define NN 50000
#define NE 800000
#define NB 196     // scan blocks over nodes
#define NBK 196    // edge chunks
#define NBUK 196   // dst buckets of 256 nodes
#define CHK 4096   // edges per chunk
#define MTOT (NBUK * NBK)   // 38416
#define MSB 151    // scan blocks over MTOT
#define CVTB 6250  // cvt blocks: NN*128/4/256
#define PREPB 418  // prep blocks
// IN=128, HID=256, LAT=64

typedef __bf16 bf16x8 __attribute__((ext_vector_type(8)));
typedef float f32x4 __attribute__((ext_vector_type(4)));
typedef unsigned short ushort_t;

__device__ inline float bf2f(uint16_t u) {
    union { uint32_t i; float f; } v; v.i = ((uint32_t)u) << 16; return v.f;
}
__device__ inline uint16_t f2bf(float f) {
    uint32_t u = __float_as_uint(f);
    u += 0x7fffu + ((u >> 16) & 1u);
    return (uint16_t)(u >> 16);
}
__device__ inline float rdf(const void* p, int i, int bf) {
    return bf ? bf2f(((const ushort_t*)p)[i]) : ((const float*)p)[i];
}

// ---------------- combined mode detection ----------------
__global__ __launch_bounds__(256) void k_modes(const int* __restrict__ ei, const ushort_t* __restrict__ xw,
                                               int* __restrict__ mode, int* __restrict__ fmode) {
    __shared__ int nz, bad;
    if (threadIdx.x == 0) { nz = 0; bad = 0; }
    __syncthreads();
    int t = threadIdx.x;
    int v = ei[2 * t + 1] | ei[2 * (t + 256) + 1] | ei[2 * (t + 512) + 1] | ei[2 * (t + 768) + 1];
    if (v) atomicOr(&nz, 1);
#pragma unroll
    for (int r = 0; r < 2; ++r) {
        uint16_t w = xw[t + 256 * r];
        int e = (w >> 7) & 0xFF;
        if (!(w == 0 || (e >= 96 && e <= 144))) atomicOr(&bad, 1);
    }
    __syncthreads();
    if (t == 0) { *mode = (nz == 0) ? 1 : 0; *fmode = (bad == 0) ? 1 : 0; }
}

// ---------------- stage1: histA ∥ cvt ∥ prep3 in one grid ----------------
__global__ __launch_bounds__(256) void k_stage1(const int* __restrict__ ei, const void* __restrict__ x,
                                                const void* __restrict__ W1l, const void* __restrict__ W1r,
                                                const void* __restrict__ W2l, const void* __restrict__ W2r,
                                                const void* __restrict__ Wd,
                                                const void* __restrict__ b1, const void* __restrict__ b2,
                                                const void* __restrict__ bd,
                                                const int* __restrict__ mode, const int* __restrict__ fmode,
                                                int* __restrict__ cntm, ushort_t* __restrict__ xb,
                                                ushort_t* __restrict__ wt, ushort_t* __restrict__ w2lt,
                                                ushort_t* __restrict__ w2rt, ushort_t* __restrict__ wdt,
                                                float* __restrict__ b1f, float* __restrict__ b2f,
                                                float* __restrict__ bdf) {
    int b = blockIdx.x, t = threadIdx.x;
    if (b < NBK) {
        // --- coarse histogram ---
        __shared__ int hist[NBUK];
        if (t < NBUK) hist[t] = 0;
        __syncthreads();
        int sh = *mode;
        for (int i = t; i < CHK; i += 256) {
            int e = b * CHK + i;
            if (e < NE) {
                int d = ei[(size_t)(NE + e) << sh];
                atomicAdd(&hist[d >> 8], 1);
            }
        }
        __syncthreads();
        if (t < NBUK) cntm[t * NBK + b] = hist[t];
    } else if (b < NBK + CVTB) {
        // --- x -> bf16 ---
        int i = (b - NBK) * 256 + t;
        if (*fmode) {
            reinterpret_cast<ushort4*>(xb)[i] = reinterpret_cast<const ushort4*>(x)[i];
        } else {
            float4 v = reinterpret_cast<const float4*>(x)[i];
            ushort4 o;
            o.x = f2bf(v.x); o.y = f2bf(v.y); o.z = f2bf(v.z); o.w = f2bf(v.w);
            reinterpret_cast<ushort4*>(xb)[i] = o;
        }
    } else {
        // --- weight/bias prep ---
        int idx = (b - NBK - CVTB) * 256 + t;
        int bf = *fmode;
        if (idx < 65536) {
            int c = idx >> 8, k = idx & 255;
            float v = (k < 128) ? rdf(W1l, k * 256 + c, bf) : rdf(W1r, (k - 128) * 256 + c, bf);
            wt[c * 256 + k] = f2bf(v);
        } else if (idx < 81920) {
            int t2 = idx - 65536;
            int c = t2 >> 8, k = t2 & 255;
            w2lt[c * 256 + k] = f2bf(rdf(W2l, k * 64 + c, bf));
        } else if (idx < 98304) {
            int t2 = idx - 81920;
            int c = t2 >> 8, k = t2 & 255;
            w2rt[c * 256 + k] = f2bf(rdf(W2r, k * 64 + c, bf));
        } else if (idx < 106496) {
            int t2 = idx - 98304;
            int c = t2 >> 6, k = t2 & 63;
            wdt[c * 64 + k] = f2bf(rdf(Wd, k * 128 + c, bf));
        } else if (idx < 106752) {
            b1f[idx - 106496] = rdf(b1, idx - 106496, bf);
        } else if (idx < 106816) {
            b2f[idx - 106752] = rdf(b2, idx - 106752, bf);
        } else if (idx < 106944) {
            bdf[idx - 106816] = rdf(bd, idx - 106816, bf);
        }
    }
}

// ---------------- generic 3-phase scan helpers ----------------
__device__ inline int block_scan256(int v, int* ws, int* btot) {
    int lane = threadIdx.x & 63, wv = threadIdx.x >> 6;
    int incl = v;
#pragma unroll
    for (int d = 1; d < 64; d <<= 1) {
        int n = __shfl_up(incl, d);
        if (lane >= d) incl += n;
    }
    if (lane == 63) ws[wv] = incl;
    __syncthreads();
    if (threadIdx.x == 0) {
        int r = 0;
#pragma unroll
        for (int k = 0; k < 4; ++k) { int t = ws[k]; ws[k] = r; r += t; }
        *btot = r;
    }
    __syncthreads();
    return ws[wv] + incl - v;
}

__global__ __launch_bounds__(256) void k_scanMA(const int* __restrict__ cntm, int* __restrict__ offm,
                                                int* __restrict__ bsM) {
    __shared__ int ws[4]; __shared__ int btot;
    int i = blockIdx.x * 256 + threadIdx.x;
    int v = (i < MTOT) ? cntm[i] : 0;
    int excl = block_scan256(v, ws, &btot);
    if (i < MTOT) offm[i] = excl;
    if (threadIdx.x == 0) bsM[blockIdx.x] = btot;
}
__global__ __launch_bounds__(256) void k_scanMB(const int* __restrict__ bsM, int* __restrict__ boM) {
    __shared__ int ws[4]; __shared__ int btot;
    int t = threadIdx.x;
    int v = (t < MSB) ? bsM[t] : 0;
    int excl = block_scan256(v, ws, &btot);
    if (t < MSB) boM[t] = excl;
}
__global__ __launch_bounds__(256) void k_scanMC(int* __restrict__ offm, const int* __restrict__ boM) {
    int i = blockIdx.x * 256 + threadIdx.x;
    if (i < MTOT) offm[i] += boM[blockIdx.x];
}

// ---------------- phase C: coarse scatter (LDS cursors) ----------------
__global__ __launch_bounds__(256) void k_scatterC(const int* __restrict__ ei, const int* __restrict__ mode,
                                                  const int* __restrict__ offm, uint32_t* __restrict__ pairs) {
    __shared__ int cur[NBUK];
    int t = threadIdx.x, blk = blockIdx.x;
    if (t < NBUK) cur[t] = offm[t * NBK + blk];
    __syncthreads();
    int sh = *mode;
    for (int i = t; i < CHK; i += 256) {
        int e = blk * CHK + i;
        if (e < NE) {
            int s = ei[(size_t)e << sh];
            int d = ei[(size_t)(NE + e) << sh];
            int pos = atomicAdd(&cur[d >> 8], 1);
            pairs[pos] = (uint32_t)s | ((uint32_t)(d & 255) << 16);
        }
    }
}

// ---------------- phase D1: per-bucket degree count ----------------
__global__ __launch_bounds__(256) void k_d1(const uint32_t* __restrict__ pairs, const int* __restrict__ offm,
                                            int* __restrict__ deg) {
    __shared__ int hist[256];
    int t = threadIdx.x, b = blockIdx.x;
    hist[t] = 0;
    __syncthreads();
    int beg = offm[b * NBK];
    int end = (b + 1 < NBUK) ? offm[(b + 1) * NBK] : NE;
    for (int i = beg + t; i < end; i += 256) {
        uint32_t p = pairs[i];
        atomicAdd(&hist[p >> 16], 1);
    }
    __syncthreads();
    int node = b * 256 + t;
    if (node < NN) deg[node] = hist[t];
}

__global__ __launch_bounds__(256) void k_scanA(const int* __restrict__ deg, int* __restrict__ rowptr,
                                               int* __restrict__ blocksum) {
    __shared__ int ws[4]; __shared__ int btot;
    int i = blockIdx.x * 256 + threadIdx.x;
    int v = (i < NN) ? deg[i] : 0;
    int excl = block_scan256(v, ws, &btot);
    if (i < NN) rowptr[i] = excl;
    if (threadIdx.x == 0) blocksum[blockIdx.x] = btot;
}
__global__ __launch_bounds__(256) void k_scanB(const int* __restrict__ blocksum, int* __restrict__ blockoff,
                                               int* __restrict__ rowptr) {
    __shared__ int ws[4]; __shared__ int btot;
    int t = threadIdx.x;
    int v = (t < NB) ? blocksum[t] : 0;
    int excl = block_scan256(v, ws, &btot);
    if (t < NB) blockoff[t] = excl;
    if (t == NB - 1) rowptr[NN] = excl + v;
}
__global__ __launch_bounds__(256) void k_scanC(int* __restrict__ rowptr, const int* __restrict__ blockoff) {
    int i = blockIdx.x * 256 + threadIdx.x;
    if (i < NN) rowptr[i] += blockoff[blockIdx.x];
}

// ---------------- phase D2: fine scatter into srclist ----------------
__global__ __launch_bounds__(256) void k_d2(const uint32_t* __restrict__ pairs, const int* __restrict__ offm,
                                            const int* __restrict__ rowptr, ushort_t* __restrict__ srclist) {
    __shared__ int cur[256];
    int t = threadIdx.x, b = blockIdx.x;
    int node = b * 256 + t;
    cur[t] = (node < NN) ? rowptr[node] : 0;
    __syncthreads();
    int beg = offm[b * NBK];
    int end = (b + 1 < NBUK) ? offm[(b + 1) * NBK] : NE;
    for (int i = beg + t; i < end; i += 256) {
        uint32_t p = pairs[i];
        int pos = atomicAdd(&cur[p >> 16], 1);
        srclist[pos] = (ushort_t)(p & 0xffff);
    }
}

// ---------------- agg1: meanx (one wave/node, 8-way edge unroll) ----------------
__global__ __launch_bounds__(256) void k_agg128(const ushort_t* __restrict__ xb, const int* __restrict__ rowptr,
                                                const ushort_t* __restrict__ srclist, ushort_t* __restrict__ out) {
    int node = (blockIdx.x * 256 + threadIdx.x) >> 6;
    int lane = threadIdx.x & 63;
    if (node >= NN) return;
    int beg = rowptr[node], end = rowptr[node + 1];
    float a0 = 0.f, a1 = 0.f;
    int j = beg;
    for (; j + 7 < end; j += 8) {
        uint32_t p[8];
#pragma unroll
        for (int u = 0; u < 8; ++u) {
            int s = srclist[j + u];
            p[u] = *reinterpret_cast<const uint32_t*>(xb + (size_t)s * 128 + lane * 2);
        }
#pragma unroll
        for (int u = 0; u < 8; ++u) {
            a0 += bf2f((uint16_t)(p[u] & 0xffff));
            a1 += bf2f((uint16_t)(p[u] >> 16));
        }
    }
    for (; j + 3 < end; j += 4) {
        uint32_t p[4];
#pragma unroll
        for (int u = 0; u < 4; ++u) {
            int s = srclist[j + u];
            p[u] = *reinterpret_cast<const uint32_t*>(xb + (size_t)s * 128 + lane * 2);
        }
#pragma unroll
        for (int u = 0; u < 4; ++u) {
            a0 += bf2f((uint16_t)(p[u] & 0xffff));
            a1 += bf2f((uint16_t)(p[u] >> 16));
        }
    }
    for (; j < end; ++j) {
        int s = srclist[j];
        uint32_t p = *reinterpret_cast<const uint32_t*>(xb + (size_t)s * 128 + lane * 2);
        a0 += bf2f((uint16_t)(p & 0xffff));
        a1 += bf2f((uint16_t)(p >> 16));
    }
    float inv = 1.0f / (float)max(end - beg, 1);
    uint32_t o = (uint32_t)f2bf(a0 * inv) | ((uint32_t)f2bf(a1 * inv) << 16);
    *reinterpret_cast<uint32_t*>(out + (size_t)node * 128 + lane * 2) = o;
}

// ---------------- GEMM1 (persistent-B MFMA) ----------------
__global__ __launch_bounds__(256, 2) void k_gemm1p(const ushort_t* __restrict__ meanx, const ushort_t* __restrict__ xb,
                                                   const ushort_t* __restrict__ wt, const float* __restrict__ b1f,
                                                   ushort_t* __restrict__ h) {
    int wv = threadIdx.x >> 6, lane = threadIdx.x & 63;
    int m = lane & 15, q = lane >> 4;
    bf16x8 B[8][4];
#pragma unroll
    for (int ks = 0; ks < 8; ++ks) {
        int kb = ks * 32 + q * 8;
#pragma unroll
        for (int ct = 0; ct < 4; ++ct)
            B[ks][ct] = *reinterpret_cast<const bf16x8*>(wt + (size_t)(wv * 64 + ct * 16 + m) * 256 + kb);
    }
    const int ntiles = NN / 16;
    for (int t = blockIdx.x; t < ntiles; t += gridDim.x) {
        int r0 = t * 16;
        int row = r0 + m;
        f32x4 acc[4];
#pragma unroll
        for (int ct = 0; ct < 4; ++ct) acc[ct] = (f32x4){0.f, 0.f, 0.f, 0.f};
#pragma unroll
        for (int ks = 0; ks < 8; ++ks) {
            int kb = ks * 32 + q * 8;
            const ushort_t* ap = (ks < 4) ? (meanx + (size_t)row * 128 + kb)
                                          : (xb + (size_t)row * 128 + (kb - 128));
            bf16x8 a = *reinterpret_cast<const bf16x8*>(ap);
#pragma unroll
            for (int ct = 0; ct < 4; ++ct)
                acc[ct] = __builtin_amdgcn_mfma_f32_16x16x32_bf16(a, B[ks][ct], acc[ct], 0, 0, 0);
        }
#pragma unroll
        for (int ct = 0; ct < 4; ++ct) {
            int c = wv * 64 + ct * 16 + m;
            float bias = b1f[c];
#pragma unroll
            for (int i = 0; i < 4; ++i) {
                int rr = r0 + q * 4 + i;
                h[(size_t)rr * 256 + c] = f2bf(fmaxf(acc[ct][i] + bias, 0.f));
            }
        }
    }
}

// ---------------- GEMM2 (persistent-B) ----------------
__global__ __launch_bounds__(256, 2) void k_gemm2p(const ushort_t* __restrict__ h,
                                                   const ushort_t* __restrict__ w2lt, const ushort_t* __restrict__ w2rt,
                                                   const float* __restrict__ b2f,
                                                   ushort_t* __restrict__ y, float* __restrict__ r) {
    int wv = threadIdx.x >> 6, lane = threadIdx.x & 63;
    int m = lane & 15, q = lane >> 4;
    int op = wv >> 1;
    int cb = (wv & 1) * 32;
    const ushort_t* wtx = op ? w2rt : w2lt;
    bf16x8 B[8][2];
#pragma unroll
    for (int ks = 0; ks < 8; ++ks) {
        int kb = ks * 32 + q * 8;
#pragma unroll
        for (int ct = 0; ct < 2; ++ct)
            B[ks][ct] = *reinterpret_cast<const bf16x8*>(wtx + (size_t)(cb + ct * 16 + m) * 256 + kb);
    }
    const int ntiles = NN / 16;
    for (int t = blockIdx.x; t < ntiles; t += gridDim.x) {
        int r0 = t * 16;
        int row = r0 + m;
        f32x4 acc[2];
        acc[0] = (f32x4){0.f, 0.f, 0.f, 0.f}; acc[1] = acc[0];
#pragma unroll
        for (int ks = 0; ks < 8; ++ks) {
            int kb = ks * 32 + q * 8;
            bf16x8 a = *reinterpret_cast<const bf16x8*>(h + (size_t)row * 256 + kb);
#pragma unroll
            for (int ct = 0; ct < 2; ++ct)
                acc[ct] = __builtin_amdgcn_mfma_f32_16x16x32_bf16(a, B[ks][ct], acc[ct], 0, 0, 0);
        }
#pragma unroll
        for (int ct = 0; ct < 2; ++ct) {
            int c = cb + ct * 16 + m;
#pragma unroll
            for (int i = 0; i < 4; ++i) {
                int rr = r0 + q * 4 + i;
                if (op == 0) y[(size_t)rr * 64 + c] = f2bf(acc[ct][i]);
                else         r[(size_t)rr * 64 + c] = acc[ct][i] + b2f[c];
            }
        }
    }
}

// ---------------- agg2y: z = mean(y) + r (4 edges in flight per half-wave) ----------------
__global__ __launch_bounds__(256) void k_agg2y(const ushort_t* __restrict__ y, const int* __restrict__ rowptr,
                                               const ushort_t* __restrict__ srclist, const float* __restrict__ r,
                                               float* __restrict__ zf, ushort_t* __restrict__ zb) {
    int node = (blockIdx.x * 256 + threadIdx.x) >> 6;
    int lane = threadIdx.x & 63;
    if (node >= NN) return;
    int half = lane >> 5, l32 = lane & 31;
    int beg = rowptr[node], end = rowptr[node + 1];
    float a0 = 0.f, a1 = 0.f;
    int j = beg + half;
    for (; j + 6 < end; j += 8) {
        uint32_t p[4];
#pragma unroll
        for (int u = 0; u < 4; ++u) {
            int s = srclist[j + 2 * u];
            p[u] = *reinterpret_cast<const uint32_t*>(y + (size_t)s * 64 + l32 * 2);
        }
#pragma unroll
        for (int u = 0; u < 4; ++u) {
            a0 += bf2f((uint16_t)(p[u] & 0xffff));
            a1 += bf2f((uint16_t)(p[u] >> 16));
        }
    }
    for (; j < end; j += 2) {
        int s = srclist[j];
        uint32_t p = *reinterpret_cast<const uint32_t*>(y + (size_t)s * 64 + l32 * 2);
        a0 += bf2f((uint16_t)(p & 0xffff));
        a1 += bf2f((uint16_t)(p >> 16));
    }
    a0 += __shfl_xor(a0, 32);
    a1 += __shfl_xor(a1, 32);
    if (half == 0) {
        float inv = 1.0f / (float)max(end - beg, 1);
        float2 rv = *reinterpret_cast<const float2*>(r + (size_t)node * 64 + l32 * 2);
        float z0 = a0 * inv + rv.x;
        float z1 = a1 * inv + rv.y;
        float2 zo; zo.x = z0; zo.y = z1;
        *reinterpret_cast<float2*>(zf + (size_t)node * 64 + l32 * 2) = zo;
        uint32_t o = (uint32_t)f2bf(z0) | ((uint32_t)f2bf(z1) << 16);
        *reinterpret_cast<uint32_t*>(zb + (size_t)node * 64 + l32 * 2) = o;
    }
}

// ---------------- GEMM3 (persistent-B) ----------------
__global__ __launch_bounds__(256, 2) void k_gemm3p(const ushort_t* __restrict__ zb, const ushort_t* __restrict__ wdt,
                                                   const float* __restrict__ bdf, float* __restrict__ xhat) {
    int wv = threadIdx.x >> 6, lane = threadIdx.x & 63;
    int m = lane & 15, q = lane >> 4;
    bf16x8 B[2][2];
#pragma unroll
    for (int ks = 0; ks < 2; ++ks) {
        int kb = ks * 32 + q * 8;
#pragma unroll
        for (int ct = 0; ct < 2; ++ct)
            B[ks][ct] = *reinterpret_cast<const bf16x8*>(wdt + (size_t)(wv * 32 + ct * 16 + m) * 64 + kb);
    }
    const int ntiles = NN / 16;
    for (int t = blockIdx.x; t < ntiles; t += gridDim.x) {
        int r0 = t * 16;
        int row = r0 + m;
        f32x4 acc[2];
        acc[0] = (f32x4){0.f, 0.f, 0.f, 0.f}; acc[1] = acc[0];
#pragma unroll
        for (int ks = 0; ks < 2; ++ks) {
            int kb = ks * 32 + q * 8;
            bf16x8 a = *reinterpret_cast<const bf16x8*>(zb + (size_t)row * 64 + kb);
#pragma unroll
            for (int ct = 0; ct < 2; ++ct)
                acc[ct] = __builtin_amdgcn_mfma_f32_16x16x32_bf16(a, B[ks][ct], acc[ct], 0, 0, 0);
        }
#pragma unroll
        for (int ct = 0; ct < 2; ++ct) {
            int c = wv * 32 + ct * 16 + m;
            float bias = bdf[c];
#pragma unroll
            for (int i = 0; i < 4; ++i) {
                int rr = r0 + q * 4 + i;
                xhat[(size_t)rr * 128 + c] = acc[ct][i] + bias;
            }
        }
    }
}

extern "C" void kernel_launch(void* const* d_in, const int* in_sizes, int n_in,
                              void* d_out, int out_size, void* d_ws, size_t ws_size,
                              hipStream_t stream) {
    // ---- order-agnostic input identification by element count ----
    const void *px = nullptr, *pei = nullptr, *pW1l = nullptr, *pW1r = nullptr,
               *pW2l = nullptr, *pW2r = nullptr, *pWd = nullptr,
               *pb1 = nullptr, *pb2 = nullptr, *pbd = nullptr;
    for (int i = 0; i < n_in; ++i) {
        const void* p = d_in[i];
        switch (in_sizes[i]) {
            case 6400000: px  = p; break;
            case 1600000: pei = p; break;
            case 32768:   if (!pW1l) pW1l = p; else pW1r = p; break;
            case 16384:   if (!pW2l) pW2l = p; else pW2r = p; break;
            case 8192:    pWd = p; break;
            case 256:     pb1 = p; break;
            case 128:     pbd = p; break;
            case 64:      pb2 = p; break;
            default: break;
        }
    }
    if (!px || !pei || !pW1l || !pW1r || !pW2l || !pW2r || !pWd || !pb1 || !pb2 || !pbd) {
        px = d_in[0]; pei = d_in[1]; pW1l = d_in[2]; pb1 = d_in[3]; pW1r = d_in[4];
        pW2l = d_in[5]; pb2 = d_in[6]; pW2r = d_in[7]; pWd = d_in[8]; pbd = d_in[9];
    }
    const int* ei = (const int*)pei;

    // ---- workspace ----
    char* base = (char*)d_ws;
    size_t off = 0;
    auto alloc = [&](size_t bytes) -> void* {
        void* r = base + off;
        off = (off + bytes + 255) & ~(size_t)255;
        return r;
    };
    int* mode     = (int*)alloc(4);
    int* fmode    = (int*)alloc(4);
    int* rowptr   = (int*)alloc((size_t)(NN + 1) * 4);
    int* blocksum = (int*)alloc((size_t)NB * 4);
    int* blockoff = (int*)alloc((size_t)NB * 4);
    int* cntm     = (int*)alloc((size_t)MTOT * 4);
    int* offm     = (int*)alloc((size_t)MTOT * 4);
    int* bsM      = (int*)alloc(256 * 4);
    int* boM      = (int*)alloc(256 * 4);
    ushort_t* srclist = (ushort_t*)alloc((size_t)NE * 2);
    ushort_t* wt   = (ushort_t*)alloc((size_t)65536 * 2);
    ushort_t* w2lt = (ushort_t*)alloc((size_t)16384 * 2);
    ushort_t* w2rt = (ushort_t*)alloc((size_t)16384 * 2);
    ushort_t* wdt  = (ushort_t*)alloc((size_t)8192 * 2);
    float* b1f    = (float*)alloc(256 * 4);
    float* b2f    = (float*)alloc(64 * 4);
    float* bdf    = (float*)alloc(128 * 4);
    ushort_t* xb  = (ushort_t*)alloc((size_t)NN * 128 * 2);   // dead after gemm1
    ushort_t* h   = (ushort_t*)alloc((size_t)NN * 256 * 2);   // written by gemm1 (late)

    // sort scratch aliases the h region (dead until gemm1p):
    uint32_t* pairs = (uint32_t*)h;
    int* deg        = (int*)((char*)h + (size_t)NE * 4 + 256);

    // outputs f32: z [NN,64] then x_hat [NN,128]
    float* out_z    = (float*)d_out;
    float* out_xhat = out_z + (size_t)NN * 64;

    ushort_t* meanx = (ushort_t*)out_xhat;
    float*    rbuf  = (float*)((char*)out_xhat + (size_t)NN * 128 * 2);
    ushort_t* y     = xb;
    ushort_t* zb    = xb + (size_t)NN * 64;

    k_modes<<<1, 256, 0, stream>>>(ei, (const ushort_t*)px, mode, fmode);

    k_stage1<<<NBK + CVTB + PREPB, 256, 0, stream>>>(ei, px, pW1l, pW1r, pW2l, pW2r, pWd, pb1, pb2, pbd,
                                                     mode, fmode, cntm, xb, wt, w2lt, w2rt, wdt,
                                                     b1f, b2f, bdf);

    k_scanMA<<<MSB, 256, 0, stream>>>(cntm, offm, bsM);
    k_scanMB<<<1, 256, 0, stream>>>(bsM, boM);
    k_scanMC<<<MSB, 256, 0, stream>>>(offm, boM);
    k_scatterC<<<NBK, 256, 0, stream>>>(ei, mode, offm, pairs);
    k_d1<<<NBUK, 256, 0, stream>>>(pairs, offm, deg);
    k_scanA<<<NB, 256, 0, stream>>>(deg, rowptr, blocksum);
    k_scanB<<<1, 256, 0, stream>>>(blocksum, blockoff, rowptr);
    k_scanC<<<NB, 256, 0, stream>>>(rowptr, blockoff);
    k_d2<<<NBUK, 256, 0, stream>>>(pairs, offm, rowptr, srclist);

    int ab = (NN + 3) / 4;
    k_agg128<<<ab, 256, 0, stream>>>(xb, rowptr, srclist, meanx);

    k_gemm1p<<<512, 256, 0, stream>>>(meanx, xb, wt, b1f, h);
    k_gemm2p<<<512, 256, 0, stream>>>(h, w2lt, w2rt, b2f, y, rbuf);
    k_agg2y<<<ab, 256, 0, stream>>>(y, rowptr, srclist, rbuf, out_z, zb);
    k_gemm3p<<<512, 256, 0, stream>>>(zb, wdt, bdf, out_xhat);
}